// Round 1
// baseline (1509.317 us; speedup 1.0000x reference)
//
#include <hip/hip_runtime.h>

#define NN 50000   // nodes
#define NE 800000  // edges
#define NH 128     // hidden
#define NG 32      // graphs
#define NL 4       // layers

// ---------------- degree histogram over targets (col) ----------------
__global__ __launch_bounds__(256) void hist_kernel(const int* __restrict__ col,
                                                   int* __restrict__ cnt) {
  int e = blockIdx.x * 256 + threadIdx.x;
  if (e < NE) atomicAdd(&cnt[col[e]], 1);
}

// dis[i] = rsqrt(deg[i]), deg = cnt + 1 (self loop)
__global__ __launch_bounds__(256) void dis_kernel(const int* __restrict__ cnt,
                                                  float* __restrict__ dis) {
  int i = blockIdx.x * 256 + threadIdx.x;
  if (i < NN) dis[i] = rsqrtf((float)(cnt[i] + 1));
}

// ---------------- single-block exclusive scan of cnt -> offs ----------------
__global__ __launch_bounds__(1024) void scan_kernel(const int* __restrict__ cnt,
                                                    int* __restrict__ offs) {
  __shared__ int buf[1024];
  __shared__ int carry;
  int tid = threadIdx.x;
  if (tid == 0) carry = 0;
  __syncthreads();
  for (int base = 0; base < NN; base += 1024) {
    int i = base + tid;
    int v = (i < NN) ? cnt[i] : 0;
    buf[tid] = v;
    __syncthreads();
    for (int off = 1; off < 1024; off <<= 1) {
      int add = (tid >= off) ? buf[tid - off] : 0;
      __syncthreads();
      buf[tid] += add;
      __syncthreads();
    }
    if (i < NN) offs[i] = carry + buf[tid] - v;
    int total = buf[1023];
    __syncthreads();
    if (tid == 0) carry += total;
    __syncthreads();
  }
}

// ---------------- CSR fill: per target node, list of (src, norm) ----------------
__global__ __launch_bounds__(256) void fill_kernel(const int* __restrict__ row,
                                                   const int* __restrict__ col,
                                                   const float* __restrict__ dis,
                                                   const int* __restrict__ offs,
                                                   int* __restrict__ fillc,
                                                   int* __restrict__ csr_src,
                                                   float* __restrict__ csr_w) {
  int e = blockIdx.x * 256 + threadIdx.x;
  if (e < NE) {
    int d = col[e];
    int s = row[e];
    int pos = offs[d] + atomicAdd(&fillc[d], 1);
    csr_src[pos] = s;
    csr_w[pos] = dis[s] * dis[d];
  }
}

// ---------------- fp32 GEMM: Y[N,128] = X[N,128] @ W[128,128]^T (+bias) ----------------
// 256 threads, 64 rows x 128 cols per block. W transposed into LDS (64 KB -> 2 blocks/CU).
__global__ __launch_bounds__(256) void gemm128(const float* __restrict__ X,
                                               const float* __restrict__ W,
                                               const float* __restrict__ bias,
                                               float* __restrict__ Y) {
  __shared__ float Ws[128 * 128];  // Ws[k*128+c] = W[c*128+k]
  int tid = threadIdx.x;
  for (int i = tid; i < 128 * 128; i += 256) {
    int c = i >> 7, k = i & 127;
    Ws[k * 128 + c] = W[i];
  }
  int row0 = blockIdx.x * 64;
  int rows = NN - row0;
  if (rows > 64) rows = 64;
  int cg = tid & 31, rg = tid >> 5;
  int c0 = cg * 4;
  const float* xptr[8];
#pragma unroll
  for (int r = 0; r < 8; ++r) {
    int rr = rg * 8 + r;
    if (rr >= rows) rr = 0;  // clamp to stay in-bounds; store is guarded
    xptr[r] = X + (size_t)(row0 + rr) * NH;
  }
  __syncthreads();
  float acc[8][4] = {};
  for (int k = 0; k < 128; k += 4) {
    float4 w0 = *(const float4*)&Ws[(k + 0) * 128 + c0];
    float4 w1 = *(const float4*)&Ws[(k + 1) * 128 + c0];
    float4 w2 = *(const float4*)&Ws[(k + 2) * 128 + c0];
    float4 w3 = *(const float4*)&Ws[(k + 3) * 128 + c0];
#pragma unroll
    for (int r = 0; r < 8; ++r) {
      float4 xv = *(const float4*)(xptr[r] + k);
      acc[r][0] += xv.x * w0.x + xv.y * w1.x + xv.z * w2.x + xv.w * w3.x;
      acc[r][1] += xv.x * w0.y + xv.y * w1.y + xv.z * w2.y + xv.w * w3.y;
      acc[r][2] += xv.x * w0.z + xv.y * w1.z + xv.z * w2.z + xv.w * w3.z;
      acc[r][3] += xv.x * w0.w + xv.y * w1.w + xv.z * w2.w + xv.w * w3.w;
    }
  }
  float4 bc = make_float4(0.f, 0.f, 0.f, 0.f);
  if (bias) bc = *(const float4*)(bias + c0);
#pragma unroll
  for (int r = 0; r < 8; ++r) {
    int rr = rg * 8 + r;
    if (rr < rows) {
      float4 o;
      o.x = acc[r][0] + bc.x;
      o.y = acc[r][1] + bc.y;
      o.z = acc[r][2] + bc.z;
      o.w = acc[r][3] + bc.w;
      *(float4*)&Y[(size_t)(row0 + rr) * NH + c0] = o;
    }
  }
}

// ---------------- fused aggregate + bias + relu + residual + layernorm ----------------
// one wave per node, float2 per lane (128 channels / 64 lanes)
__global__ __launch_bounds__(256) void aggregate_kernel(
    const float* __restrict__ t, float* __restrict__ h,
    const float* __restrict__ dis, const int* __restrict__ offs,
    const int* __restrict__ cnt, const int* __restrict__ csr_src,
    const float* __restrict__ csr_w, const float* __restrict__ bias,
    const float* __restrict__ gamma, const float* __restrict__ beta) {
  int node = blockIdx.x * 4 + (threadIdx.x >> 6);
  int lane = threadIdx.x & 63;
  if (node >= NN) return;
  const float2* t2 = (const float2*)t;
  float2* h2 = (float2*)h;
  float dii = dis[node];
  float sl = dii * dii;  // self-loop norm
  float2 tv = t2[(size_t)node * 64 + lane];
  float a0 = tv.x * sl, a1 = tv.y * sl;
  int s0 = offs[node];
  int e = cnt[node];
  for (int j = 0; j < e; ++j) {
    int src = csr_src[s0 + j];
    float w = csr_w[s0 + j];
    float2 m = t2[(size_t)src * 64 + lane];
    a0 += m.x * w;
    a1 += m.y * w;
  }
  float2 bv = ((const float2*)bias)[lane];
  a0 = fmaxf(a0 + bv.x, 0.f);
  a1 = fmaxf(a1 + bv.y, 0.f);
  float2 hv = h2[(size_t)node * 64 + lane];
  float v0 = hv.x + a0, v1 = hv.y + a1;
  float s = v0 + v1, s2 = v0 * v0 + v1 * v1;
#pragma unroll
  for (int off = 32; off; off >>= 1) {
    s += __shfl_down(s, off, 64);
    s2 += __shfl_down(s2, off, 64);
  }
  s = __shfl(s, 0, 64);
  s2 = __shfl(s2, 0, 64);
  float mean = s * (1.f / 128.f);
  float var = fmaxf(s2 * (1.f / 128.f) - mean * mean, 0.f);
  float inv = rsqrtf(var + 1e-5f);
  float2 gv = ((const float2*)gamma)[lane];
  float2 bt = ((const float2*)beta)[lane];
  float2 o;
  o.x = (v0 - mean) * inv * gv.x + bt.x;
  o.y = (v1 - mean) * inv * gv.y + bt.y;
  h2[(size_t)node * 64 + lane] = o;
}

// ---------------- out = h @ W_out^T, mean-pooled per graph ----------------
__global__ __launch_bounds__(256) void pool_kernel(const float* __restrict__ h,
                                                   const float* __restrict__ Wout,
                                                   const int* __restrict__ batch,
                                                   float* __restrict__ gsum,
                                                   int* __restrict__ gcnt) {
  int node = blockIdx.x * 4 + (threadIdx.x >> 6);
  int lane = threadIdx.x & 63;
  if (node >= NN) return;
  const float2* h2 = (const float2*)h;
  const float2* w2 = (const float2*)Wout;
  float2 hv = h2[(size_t)node * 64 + lane];
  float2 wv = w2[lane];
  float s = hv.x * wv.x + hv.y * wv.y;
#pragma unroll
  for (int off = 32; off; off >>= 1) s += __shfl_down(s, off, 64);
  if (lane == 0) {
    int g = batch[node];
    atomicAdd(&gsum[g], s);
    atomicAdd(&gcnt[g], 1);
  }
}

__global__ void finalize_kernel(const float* __restrict__ gsum,
                                const int* __restrict__ gcnt,
                                float* __restrict__ out) {
  int g = threadIdx.x;
  if (g < NG) out[g] = gsum[g] / fmaxf((float)gcnt[g], 1.0f);
}

extern "C" void kernel_launch(void* const* d_in, const int* in_sizes, int n_in,
                              void* d_out, int out_size, void* d_ws, size_t ws_size,
                              hipStream_t stream) {
  const float* x = (const float*)d_in[0];
  const int* eidx = (const int*)d_in[1];
  const int* batch = (const int*)d_in[2];
  const float* W_emb = (const float*)d_in[3];
  const float* b_emb = (const float*)d_in[4];
  const float* W_layers = (const float*)d_in[5];
  const float* b_layers = (const float*)d_in[6];
  const float* ln_gamma = (const float*)d_in[7];
  const float* ln_beta = (const float*)d_in[8];
  const float* W_out = (const float*)d_in[9];
  float* out = (float*)d_out;

  char* ws = (char*)d_ws;
  float* t = (float*)ws;        ws += (size_t)NN * NH * 4;
  float* h = (float*)ws;        ws += (size_t)NN * NH * 4;
  float* dis = (float*)ws;      ws += (size_t)NN * 4;
  float* csr_w = (float*)ws;    ws += (size_t)NE * 4;
  int* csr_src = (int*)ws;      ws += (size_t)NE * 4;
  int* offs = (int*)ws;         ws += (size_t)NN * 4;
  char* zero_base = ws;
  int* cnt = (int*)ws;          ws += (size_t)NN * 4;
  int* fillc = (int*)ws;        ws += (size_t)NN * 4;
  float* gsum = (float*)ws;     ws += (size_t)NG * 4;
  int* gcnt = (int*)ws;         ws += (size_t)NG * 4;
  size_t zero_bytes = (size_t)(ws - zero_base);
  hipMemsetAsync(zero_base, 0, zero_bytes, stream);

  const int* erow = eidx;        // edge_index[0] = sources
  const int* ecol = eidx + NE;   // edge_index[1] = targets

  hist_kernel<<<(NE + 255) / 256, 256, 0, stream>>>(ecol, cnt);
  dis_kernel<<<(NN + 255) / 256, 256, 0, stream>>>(cnt, dis);
  scan_kernel<<<1, 1024, 0, stream>>>(cnt, offs);
  fill_kernel<<<(NE + 255) / 256, 256, 0, stream>>>(erow, ecol, dis, offs, fillc,
                                                    csr_src, csr_w);
  // embedding
  gemm128<<<(NN + 63) / 64, 256, 0, stream>>>(x, W_emb, b_emb, h);
  // 4 GCN layers
  for (int l = 0; l < NL; ++l) {
    gemm128<<<(NN + 63) / 64, 256, 0, stream>>>(h, W_layers + (size_t)l * NH * NH,
                                                nullptr, t);
    aggregate_kernel<<<(NN + 3) / 4, 256, 0, stream>>>(
        t, h, dis, offs, cnt, csr_src, csr_w, b_layers + (size_t)l * NH,
        ln_gamma + (size_t)l * NH, ln_beta + (size_t)l * NH);
  }
  // readout + mean pool
  pool_kernel<<<(NN + 3) / 4, 256, 0, stream>>>(h, W_out, batch, gsum, gcnt);
  finalize_kernel<<<1, 64, 0, stream>>>(gsum, gcnt, out);
}

// Round 2
// 897.628 us; speedup vs baseline: 1.6815x; 1.6815x over previous
//
#include <hip/hip_runtime.h>

#define NN 50000   // nodes
#define NE 800000  // edges
#define NH 128     // hidden
#define NG 32      // graphs
#define NL 4       // layers

// ---------------- degree histogram over targets (col) ----------------
__global__ __launch_bounds__(256) void hist_kernel(const int* __restrict__ col,
                                                   int* __restrict__ cnt) {
  int e = blockIdx.x * 256 + threadIdx.x;
  if (e < NE) atomicAdd(&cnt[col[e]], 1);
}

// dis[i] = rsqrt(deg[i]), deg = cnt + 1 (self loop)
__global__ __launch_bounds__(256) void dis_kernel(const int* __restrict__ cnt,
                                                  float* __restrict__ dis) {
  int i = blockIdx.x * 256 + threadIdx.x;
  if (i < NN) dis[i] = rsqrtf((float)(cnt[i] + 1));
}

// ---------------- single-block exclusive scan of cnt -> offs ----------------
// wave-shuffle scans: 4 barriers per 1024-chunk instead of ~22
__global__ __launch_bounds__(1024) void scan_kernel(const int* __restrict__ cnt,
                                                    int* __restrict__ offs) {
  __shared__ int wsums[16];
  __shared__ int carry;
  int tid = threadIdx.x;
  int wave = tid >> 6, lane = tid & 63;
  if (tid == 0) carry = 0;
  __syncthreads();
  for (int base = 0; base < NN; base += 1024) {
    int i = base + tid;
    int v = (i < NN) ? cnt[i] : 0;
    // inclusive scan within wave (64 lanes)
    int x = v;
#pragma unroll
    for (int off = 1; off < 64; off <<= 1) {
      int y = __shfl_up(x, off, 64);
      if (lane >= off) x += y;
    }
    if (lane == 63) wsums[wave] = x;
    __syncthreads();
    if (tid < 16) {  // inclusive scan of 16 wave sums in lanes 0..15
      int w = wsums[tid];
#pragma unroll
      for (int off = 1; off < 16; off <<= 1) {
        int y = __shfl_up(w, off, 16);
        if (tid >= off) w += y;
      }
      wsums[tid] = w;
    }
    __syncthreads();
    int wprefix = wave ? wsums[wave - 1] : 0;
    if (i < NN) offs[i] = carry + wprefix + x - v;  // exclusive
    int total = wsums[15];
    __syncthreads();
    if (tid == 0) carry += total;
    __syncthreads();
  }
}

// ---------------- CSR fill: per target node, list of (src, norm) ----------------
__global__ __launch_bounds__(256) void fill_kernel(const int* __restrict__ row,
                                                   const int* __restrict__ col,
                                                   const float* __restrict__ dis,
                                                   const int* __restrict__ offs,
                                                   int* __restrict__ fillc,
                                                   int* __restrict__ csr_src,
                                                   float* __restrict__ csr_w) {
  int e = blockIdx.x * 256 + threadIdx.x;
  if (e < NE) {
    int d = col[e];
    int s = row[e];
    int pos = offs[d] + atomicAdd(&fillc[d], 1);
    csr_src[pos] = s;
    csr_w[pos] = dis[s] * dis[d];
  }
}

// ---------------- fp32 GEMM: Y[N,128] = X[N,128] @ W[128,128]^T (+bias) ----------------
__global__ __launch_bounds__(256) void gemm128(const float* __restrict__ X,
                                               const float* __restrict__ W,
                                               const float* __restrict__ bias,
                                               float* __restrict__ Y) {
  __shared__ float Ws[128 * 128];  // Ws[k*128+c] = W[c*128+k]
  int tid = threadIdx.x;
  for (int i = tid; i < 128 * 128; i += 256) {
    int c = i >> 7, k = i & 127;
    Ws[k * 128 + c] = W[i];
  }
  int row0 = blockIdx.x * 64;
  int rows = NN - row0;
  if (rows > 64) rows = 64;
  int cg = tid & 31, rg = tid >> 5;
  int c0 = cg * 4;
  const float* xptr[8];
#pragma unroll
  for (int r = 0; r < 8; ++r) {
    int rr = rg * 8 + r;
    if (rr >= rows) rr = 0;  // clamp to stay in-bounds; store is guarded
    xptr[r] = X + (size_t)(row0 + rr) * NH;
  }
  __syncthreads();
  float acc[8][4] = {};
  for (int k = 0; k < 128; k += 4) {
    float4 w0 = *(const float4*)&Ws[(k + 0) * 128 + c0];
    float4 w1 = *(const float4*)&Ws[(k + 1) * 128 + c0];
    float4 w2 = *(const float4*)&Ws[(k + 2) * 128 + c0];
    float4 w3 = *(const float4*)&Ws[(k + 3) * 128 + c0];
#pragma unroll
    for (int r = 0; r < 8; ++r) {
      float4 xv = *(const float4*)(xptr[r] + k);
      acc[r][0] += xv.x * w0.x + xv.y * w1.x + xv.z * w2.x + xv.w * w3.x;
      acc[r][1] += xv.x * w0.y + xv.y * w1.y + xv.z * w2.y + xv.w * w3.y;
      acc[r][2] += xv.x * w0.z + xv.y * w1.z + xv.z * w2.z + xv.w * w3.z;
      acc[r][3] += xv.x * w0.w + xv.y * w1.w + xv.z * w2.w + xv.w * w3.w;
    }
  }
  float4 bc = make_float4(0.f, 0.f, 0.f, 0.f);
  if (bias) bc = *(const float4*)(bias + c0);
#pragma unroll
  for (int r = 0; r < 8; ++r) {
    int rr = rg * 8 + r;
    if (rr < rows) {
      float4 o;
      o.x = acc[r][0] + bc.x;
      o.y = acc[r][1] + bc.y;
      o.z = acc[r][2] + bc.z;
      o.w = acc[r][3] + bc.w;
      *(float4*)&Y[(size_t)(row0 + rr) * NH + c0] = o;
    }
  }
}

// ---------------- fused aggregate + bias + relu + residual + layernorm ----------------
__global__ __launch_bounds__(256) void aggregate_kernel(
    const float* __restrict__ t, float* __restrict__ h,
    const float* __restrict__ dis, const int* __restrict__ offs,
    const int* __restrict__ cnt, const int* __restrict__ csr_src,
    const float* __restrict__ csr_w, const float* __restrict__ bias,
    const float* __restrict__ gamma, const float* __restrict__ beta) {
  int node = blockIdx.x * 4 + (threadIdx.x >> 6);
  int lane = threadIdx.x & 63;
  if (node >= NN) return;
  const float2* t2 = (const float2*)t;
  float2* h2 = (float2*)h;
  float dii = dis[node];
  float sl = dii * dii;  // self-loop norm
  float2 tv = t2[(size_t)node * 64 + lane];
  float a0 = tv.x * sl, a1 = tv.y * sl;
  int s0 = offs[node];
  int e = cnt[node];
  for (int j = 0; j < e; ++j) {
    int src = csr_src[s0 + j];
    float w = csr_w[s0 + j];
    float2 m = t2[(size_t)src * 64 + lane];
    a0 += m.x * w;
    a1 += m.y * w;
  }
  float2 bv = ((const float2*)bias)[lane];
  a0 = fmaxf(a0 + bv.x, 0.f);
  a1 = fmaxf(a1 + bv.y, 0.f);
  float2 hv = h2[(size_t)node * 64 + lane];
  float v0 = hv.x + a0, v1 = hv.y + a1;
  float s = v0 + v1, s2 = v0 * v0 + v1 * v1;
#pragma unroll
  for (int off = 32; off; off >>= 1) {
    s += __shfl_down(s, off, 64);
    s2 += __shfl_down(s2, off, 64);
  }
  s = __shfl(s, 0, 64);
  s2 = __shfl(s2, 0, 64);
  float mean = s * (1.f / 128.f);
  float var = fmaxf(s2 * (1.f / 128.f) - mean * mean, 0.f);
  float inv = rsqrtf(var + 1e-5f);
  float2 gv = ((const float2*)gamma)[lane];
  float2 bt = ((const float2*)beta)[lane];
  float2 o;
  o.x = (v0 - mean) * inv * gv.x + bt.x;
  o.y = (v1 - mean) * inv * gv.y + bt.y;
  h2[(size_t)node * 64 + lane] = o;
}

// ---------------- stage 1: per-node dot with W_out (no atomics) ----------------
__global__ __launch_bounds__(256) void pool1_kernel(const float* __restrict__ h,
                                                    const float* __restrict__ Wout,
                                                    float* __restrict__ nodeval) {
  int node = blockIdx.x * 4 + (threadIdx.x >> 6);
  int lane = threadIdx.x & 63;
  if (node >= NN) return;
  const float2* h2 = (const float2*)h;
  const float2* w2 = (const float2*)Wout;
  float2 hv = h2[(size_t)node * 64 + lane];
  float2 wv = w2[lane];
  float s = hv.x * wv.x + hv.y * wv.y;
#pragma unroll
  for (int off = 32; off; off >>= 1) s += __shfl_down(s, off, 64);
  if (lane == 0) nodeval[node] = s;
}

// ---------------- stage 2: LDS-binned segment reduction over sorted batch ----------
__global__ __launch_bounds__(256) void reduce_pool_kernel(
    const float* __restrict__ nodeval, const int* __restrict__ batch,
    float* __restrict__ gsum, int* __restrict__ gcnt) {
  __shared__ float bins[NG];
  __shared__ int cbins[NG];
  int tid = threadIdx.x;
  if (tid < NG) {
    bins[tid] = 0.f;
    cbins[tid] = 0;
  }
  __syncthreads();
  int i = blockIdx.x * 256 + tid;
  if (i < NN) {
    int g = batch[i];
    atomicAdd(&bins[g], nodeval[i]);
    atomicAdd(&cbins[g], 1);
  }
  __syncthreads();
  if (tid < NG) {
    if (cbins[tid]) {
      atomicAdd(&gsum[tid], bins[tid]);
      atomicAdd(&gcnt[tid], cbins[tid]);
    }
  }
}

__global__ void finalize_kernel(const float* __restrict__ gsum,
                                const int* __restrict__ gcnt,
                                float* __restrict__ out) {
  int g = threadIdx.x;
  if (g < NG) out[g] = gsum[g] / fmaxf((float)gcnt[g], 1.0f);
}

extern "C" void kernel_launch(void* const* d_in, const int* in_sizes, int n_in,
                              void* d_out, int out_size, void* d_ws, size_t ws_size,
                              hipStream_t stream) {
  const float* x = (const float*)d_in[0];
  const int* eidx = (const int*)d_in[1];
  const int* batch = (const int*)d_in[2];
  const float* W_emb = (const float*)d_in[3];
  const float* b_emb = (const float*)d_in[4];
  const float* W_layers = (const float*)d_in[5];
  const float* b_layers = (const float*)d_in[6];
  const float* ln_gamma = (const float*)d_in[7];
  const float* ln_beta = (const float*)d_in[8];
  const float* W_out = (const float*)d_in[9];
  float* out = (float*)d_out;

  char* ws = (char*)d_ws;
  float* t = (float*)ws;        ws += (size_t)NN * NH * 4;
  float* h = (float*)ws;        ws += (size_t)NN * NH * 4;
  float* dis = (float*)ws;      ws += (size_t)NN * 4;
  float* csr_w = (float*)ws;    ws += (size_t)NE * 4;
  int* csr_src = (int*)ws;      ws += (size_t)NE * 4;
  int* offs = (int*)ws;         ws += (size_t)NN * 4;
  float* nodeval = (float*)ws;  ws += (size_t)NN * 4;
  char* zero_base = ws;
  int* cnt = (int*)ws;          ws += (size_t)NN * 4;
  int* fillc = (int*)ws;        ws += (size_t)NN * 4;
  float* gsum = (float*)ws;     ws += (size_t)NG * 4;
  int* gcnt = (int*)ws;         ws += (size_t)NG * 4;
  size_t zero_bytes = (size_t)(ws - zero_base);
  hipMemsetAsync(zero_base, 0, zero_bytes, stream);

  const int* erow = eidx;        // edge_index[0] = sources
  const int* ecol = eidx + NE;   // edge_index[1] = targets

  hist_kernel<<<(NE + 255) / 256, 256, 0, stream>>>(ecol, cnt);
  dis_kernel<<<(NN + 255) / 256, 256, 0, stream>>>(cnt, dis);
  scan_kernel<<<1, 1024, 0, stream>>>(cnt, offs);
  fill_kernel<<<(NE + 255) / 256, 256, 0, stream>>>(erow, ecol, dis, offs, fillc,
                                                    csr_src, csr_w);
  // embedding
  gemm128<<<(NN + 63) / 64, 256, 0, stream>>>(x, W_emb, b_emb, h);
  // 4 GCN layers
  for (int l = 0; l < NL; ++l) {
    gemm128<<<(NN + 63) / 64, 256, 0, stream>>>(h, W_layers + (size_t)l * NH * NH,
                                                nullptr, t);
    aggregate_kernel<<<(NN + 3) / 4, 256, 0, stream>>>(
        t, h, dis, offs, cnt, csr_src, csr_w, b_layers + (size_t)l * NH,
        ln_gamma + (size_t)l * NH, ln_beta + (size_t)l * NH);
  }
  // readout + two-stage mean pool
  pool1_kernel<<<(NN + 3) / 4, 256, 0, stream>>>(h, W_out, nodeval);
  reduce_pool_kernel<<<(NN + 255) / 256, 256, 0, stream>>>(nodeval, batch, gsum,
                                                           gcnt);
  finalize_kernel<<<1, 64, 0, stream>>>(gsum, gcnt, out);
}

// Round 3
// 752.399 us; speedup vs baseline: 2.0060x; 1.1930x over previous
//
#include <hip/hip_runtime.h>
#include <hip/hip_fp16.h>

#define NN 50000   // nodes
#define NE 800000  // edges
#define NH 128     // hidden
#define NG 32      // graphs
#define NL 4       // layers

typedef __attribute__((ext_vector_type(8))) short bf16x8;
typedef __attribute__((ext_vector_type(4))) float f32x4;

__device__ inline short f2bf(float x) {
  union { float f; unsigned u; } v;
  v.f = x;
  unsigned r = v.u + 0x7FFF + ((v.u >> 16) & 1);
  return (short)(r >> 16);
}
__device__ inline float bf2f(short s) {
  union { unsigned u; float f; } v;
  v.u = ((unsigned)(unsigned short)s) << 16;
  return v.f;
}

// ---------------- split W into bf16 hi/lo ----------------
__global__ __launch_bounds__(256) void prep_split(const float* __restrict__ W,
                                                  short* __restrict__ hi,
                                                  short* __restrict__ lo, int n) {
  int i = blockIdx.x * 256 + threadIdx.x;
  if (i < n) {
    float x = W[i];
    short h = f2bf(x);
    hi[i] = h;
    lo[i] = f2bf(x - bf2f(h));
  }
}

// ---------------- degree histogram over targets (col) ----------------
__global__ __launch_bounds__(256) void hist_kernel(const int* __restrict__ col,
                                                   int* __restrict__ cnt) {
  int e = blockIdx.x * 256 + threadIdx.x;
  if (e < NE) atomicAdd(&cnt[col[e]], 1);
}

// dis[i] = rsqrt(deg[i]), deg = cnt + 1 (self loop)
__global__ __launch_bounds__(256) void dis_kernel(const int* __restrict__ cnt,
                                                  float* __restrict__ dis) {
  int i = blockIdx.x * 256 + threadIdx.x;
  if (i < NN) dis[i] = rsqrtf((float)(cnt[i] + 1));
}

// ---------------- single-block exclusive scan of cnt -> offs ----------------
__global__ __launch_bounds__(1024) void scan_kernel(const int* __restrict__ cnt,
                                                    int* __restrict__ offs) {
  __shared__ int wsums[16];
  __shared__ int carry;
  int tid = threadIdx.x;
  int wave = tid >> 6, lane = tid & 63;
  if (tid == 0) carry = 0;
  __syncthreads();
  for (int base = 0; base < NN; base += 1024) {
    int i = base + tid;
    int v = (i < NN) ? cnt[i] : 0;
    int x = v;
#pragma unroll
    for (int off = 1; off < 64; off <<= 1) {
      int y = __shfl_up(x, off, 64);
      if (lane >= off) x += y;
    }
    if (lane == 63) wsums[wave] = x;
    __syncthreads();
    if (tid < 16) {
      int w = wsums[tid];
#pragma unroll
      for (int off = 1; off < 16; off <<= 1) {
        int y = __shfl_up(w, off, 16);
        if (tid >= off) w += y;
      }
      wsums[tid] = w;
    }
    __syncthreads();
    int wprefix = wave ? wsums[wave - 1] : 0;
    if (i < NN) offs[i] = carry + wprefix + x - v;
    int total = wsums[15];
    __syncthreads();
    if (tid == 0) carry += total;
    __syncthreads();
  }
}

// ---------------- CSR fill ----------------
__global__ __launch_bounds__(256) void fill_kernel(const int* __restrict__ row,
                                                   const int* __restrict__ col,
                                                   const float* __restrict__ dis,
                                                   const int* __restrict__ offs,
                                                   int* __restrict__ fillc,
                                                   int* __restrict__ csr_src,
                                                   float* __restrict__ csr_w) {
  int e = blockIdx.x * 256 + threadIdx.x;
  if (e < NE) {
    int d = col[e];
    int s = row[e];
    int pos = offs[d] + atomicAdd(&fillc[d], 1);
    csr_src[pos] = s;
    csr_w[pos] = dis[s] * dis[d];
  }
}

// ---------------- split-bf16 MFMA GEMM: Y[N,128] = X[N,128] @ W[128,128]^T -------
// no LDS: A fragments from global X (fp32 -> bf16 hi/lo in regs),
// B fragments from precomputed Whi/Wlo (L1/L2 resident, 64 KB).
// block = 256 thr = 4 waves, wave owns 16 rows x 128 cols (8 n-tiles of 16x16).
template <bool HALF_OUT>
__global__ __launch_bounds__(256) void gemm_mfma(const float* __restrict__ X,
                                                 const short* __restrict__ Whi,
                                                 const short* __restrict__ Wlo,
                                                 const float* __restrict__ bias,
                                                 float* __restrict__ Yf,
                                                 __half* __restrict__ Yh) {
  int wave = threadIdx.x >> 6, lane = threadIdx.x & 63;
  int quad = lane >> 4, r16 = lane & 15;
  int m0 = blockIdx.x * 64 + wave * 16;
  if (m0 >= NN) return;  // NN % 16 == 0, active waves have 16 full rows
  int mA = m0 + r16;  // A row this lane loads

  f32x4 acc[8];
#pragma unroll
  for (int t = 0; t < 8; ++t) acc[t] = (f32x4){0.f, 0.f, 0.f, 0.f};

#pragma unroll
  for (int ks = 0; ks < 4; ++ks) {
    int klane = ks * 32 + quad * 8;  // this lane's 8-wide k slice
    // A fragment: X[mA][klane .. klane+8), fp32 -> bf16 hi/lo
    const float* xr = X + (size_t)mA * NH + klane;
    float4 a0 = *(const float4*)xr;
    float4 a1 = *(const float4*)(xr + 4);
    float af[8] = {a0.x, a0.y, a0.z, a0.w, a1.x, a1.y, a1.z, a1.w};
    bf16x8 ahi, alo;
#pragma unroll
    for (int j = 0; j < 8; ++j) {
      short h = f2bf(af[j]);
      ahi[j] = h;
      alo[j] = f2bf(af[j] - bf2f(h));
    }
#pragma unroll
    for (int t = 0; t < 8; ++t) {
      int n = t * 16 + r16;
      bf16x8 bhi = *(const bf16x8*)(Whi + n * NH + klane);
      bf16x8 blo = *(const bf16x8*)(Wlo + n * NH + klane);
      acc[t] = __builtin_amdgcn_mfma_f32_16x16x32_bf16(ahi, bhi, acc[t], 0, 0, 0);
      acc[t] = __builtin_amdgcn_mfma_f32_16x16x32_bf16(alo, bhi, acc[t], 0, 0, 0);
      acc[t] = __builtin_amdgcn_mfma_f32_16x16x32_bf16(ahi, blo, acc[t], 0, 0, 0);
    }
  }
  // epilogue: lane holds D[m = quad*4 + r][n = t*16 + r16]
  int mrow = m0 + quad * 4;
#pragma unroll
  for (int t = 0; t < 8; ++t) {
    int col = t * 16 + r16;
    float bb = HALF_OUT ? 0.f : (bias ? bias[col] : 0.f);
#pragma unroll
    for (int r = 0; r < 4; ++r) {
      float v = acc[t][r] + bb;
      if (HALF_OUT)
        Yh[(size_t)(mrow + r) * NH + col] = __float2half(v);
      else
        Yf[(size_t)(mrow + r) * NH + col] = v;
    }
  }
}

// ---------------- fused aggregate + bias + relu + residual + layernorm ----------
// one wave per node; t is fp16 (half the gather bytes), h stays fp32
__global__ __launch_bounds__(256) void aggregate_kernel(
    const __half* __restrict__ t, float* __restrict__ h,
    const float* __restrict__ dis, const int* __restrict__ offs,
    const int* __restrict__ cnt, const int* __restrict__ csr_src,
    const float* __restrict__ csr_w, const float* __restrict__ bias,
    const float* __restrict__ gamma, const float* __restrict__ beta) {
  int node = blockIdx.x * 4 + (threadIdx.x >> 6);
  int lane = threadIdx.x & 63;
  if (node >= NN) return;
  const __half2* t2 = (const __half2*)t;
  float2* h2 = (float2*)h;
  float dii = dis[node];
  float sl = dii * dii;  // self-loop norm
  float2 tv = __half22float2(t2[(size_t)node * 64 + lane]);
  float a0 = tv.x * sl, a1 = tv.y * sl;
  int s0 = offs[node];
  int e = cnt[node];
  for (int j = 0; j < e; ++j) {
    int src = csr_src[s0 + j];
    float w = csr_w[s0 + j];
    float2 m = __half22float2(t2[(size_t)src * 64 + lane]);
    a0 += m.x * w;
    a1 += m.y * w;
  }
  float2 bv = ((const float2*)bias)[lane];
  a0 = fmaxf(a0 + bv.x, 0.f);
  a1 = fmaxf(a1 + bv.y, 0.f);
  float2 hv = h2[(size_t)node * 64 + lane];
  float v0 = hv.x + a0, v1 = hv.y + a1;
  float s = v0 + v1, s2 = v0 * v0 + v1 * v1;
#pragma unroll
  for (int off = 32; off; off >>= 1) {
    s += __shfl_down(s, off, 64);
    s2 += __shfl_down(s2, off, 64);
  }
  s = __shfl(s, 0, 64);
  s2 = __shfl(s2, 0, 64);
  float mean = s * (1.f / 128.f);
  float var = fmaxf(s2 * (1.f / 128.f) - mean * mean, 0.f);
  float inv = rsqrtf(var + 1e-5f);
  float2 gv = ((const float2*)gamma)[lane];
  float2 bt = ((const float2*)beta)[lane];
  float2 o;
  o.x = (v0 - mean) * inv * gv.x + bt.x;
  o.y = (v1 - mean) * inv * gv.y + bt.y;
  h2[(size_t)node * 64 + lane] = o;
}

// ---------------- stage 1: per-node dot with W_out ----------------
__global__ __launch_bounds__(256) void pool1_kernel(const float* __restrict__ h,
                                                    const float* __restrict__ Wout,
                                                    float* __restrict__ nodeval) {
  int node = blockIdx.x * 4 + (threadIdx.x >> 6);
  int lane = threadIdx.x & 63;
  if (node >= NN) return;
  const float2* h2 = (const float2*)h;
  const float2* w2 = (const float2*)Wout;
  float2 hv = h2[(size_t)node * 64 + lane];
  float2 wv = w2[lane];
  float s = hv.x * wv.x + hv.y * wv.y;
#pragma unroll
  for (int off = 32; off; off >>= 1) s += __shfl_down(s, off, 64);
  if (lane == 0) nodeval[node] = s;
}

// ---------------- stage 2: LDS-binned segment reduction ----------------
__global__ __launch_bounds__(256) void reduce_pool_kernel(
    const float* __restrict__ nodeval, const int* __restrict__ batch,
    float* __restrict__ gsum, int* __restrict__ gcnt) {
  __shared__ float bins[NG];
  __shared__ int cbins[NG];
  int tid = threadIdx.x;
  if (tid < NG) {
    bins[tid] = 0.f;
    cbins[tid] = 0;
  }
  __syncthreads();
  int i = blockIdx.x * 256 + tid;
  if (i < NN) {
    int g = batch[i];
    atomicAdd(&bins[g], nodeval[i]);
    atomicAdd(&cbins[g], 1);
  }
  __syncthreads();
  if (tid < NG) {
    if (cbins[tid]) {
      atomicAdd(&gsum[tid], bins[tid]);
      atomicAdd(&gcnt[tid], cbins[tid]);
    }
  }
}

__global__ void finalize_kernel(const float* __restrict__ gsum,
                                const int* __restrict__ gcnt,
                                float* __restrict__ out) {
  int g = threadIdx.x;
  if (g < NG) out[g] = gsum[g] / fmaxf((float)gcnt[g], 1.0f);
}

extern "C" void kernel_launch(void* const* d_in, const int* in_sizes, int n_in,
                              void* d_out, int out_size, void* d_ws, size_t ws_size,
                              hipStream_t stream) {
  const float* x = (const float*)d_in[0];
  const int* eidx = (const int*)d_in[1];
  const int* batch = (const int*)d_in[2];
  const float* W_emb = (const float*)d_in[3];
  const float* b_emb = (const float*)d_in[4];
  const float* W_layers = (const float*)d_in[5];
  const float* b_layers = (const float*)d_in[6];
  const float* ln_gamma = (const float*)d_in[7];
  const float* ln_beta = (const float*)d_in[8];
  const float* W_out = (const float*)d_in[9];
  float* out = (float*)d_out;

  char* ws = (char*)d_ws;
  __half* t = (__half*)ws;      ws += (size_t)NN * NH * 2;   // fp16 messages
  float* h = (float*)ws;        ws += (size_t)NN * NH * 4;
  short* Whi = (short*)ws;      ws += (size_t)5 * NH * NH * 2;
  short* Wlo = (short*)ws;      ws += (size_t)5 * NH * NH * 2;
  float* dis = (float*)ws;      ws += (size_t)NN * 4;
  float* csr_w = (float*)ws;    ws += (size_t)NE * 4;
  int* csr_src = (int*)ws;      ws += (size_t)NE * 4;
  int* offs = (int*)ws;         ws += (size_t)NN * 4;
  float* nodeval = (float*)ws;  ws += (size_t)NN * 4;
  char* zero_base = ws;
  int* cnt = (int*)ws;          ws += (size_t)NN * 4;
  int* fillc = (int*)ws;        ws += (size_t)NN * 4;
  float* gsum = (float*)ws;     ws += (size_t)NG * 4;
  int* gcnt = (int*)ws;         ws += (size_t)NG * 4;
  size_t zero_bytes = (size_t)(ws - zero_base);
  hipMemsetAsync(zero_base, 0, zero_bytes, stream);

  const int* erow = eidx;        // edge_index[0] = sources
  const int* ecol = eidx + NE;   // edge_index[1] = targets

  // W split precompute (emb -> slot 0, layers -> slots 1..4)
  prep_split<<<(NH * NH + 255) / 256, 256, 0, stream>>>(W_emb, Whi, Wlo, NH * NH);
  prep_split<<<(NL * NH * NH + 255) / 256, 256, 0, stream>>>(
      W_layers, Whi + NH * NH, Wlo + NH * NH, NL * NH * NH);

  hist_kernel<<<(NE + 255) / 256, 256, 0, stream>>>(ecol, cnt);
  dis_kernel<<<(NN + 255) / 256, 256, 0, stream>>>(cnt, dis);
  scan_kernel<<<1, 1024, 0, stream>>>(cnt, offs);
  fill_kernel<<<(NE + 255) / 256, 256, 0, stream>>>(erow, ecol, dis, offs, fillc,
                                                    csr_src, csr_w);
  int gblk = (NN + 63) / 64;
  // embedding: h = x @ W_emb^T + b_emb  (fp32 out)
  gemm_mfma<false><<<gblk, 256, 0, stream>>>(x, Whi, Wlo, b_emb, h, nullptr);
  // 4 GCN layers
  for (int l = 0; l < NL; ++l) {
    gemm_mfma<true><<<gblk, 256, 0, stream>>>(
        h, Whi + (size_t)(l + 1) * NH * NH, Wlo + (size_t)(l + 1) * NH * NH,
        nullptr, nullptr, t);
    aggregate_kernel<<<(NN + 3) / 4, 256, 0, stream>>>(
        t, h, dis, offs, cnt, csr_src, csr_w, b_layers + (size_t)l * NH,
        ln_gamma + (size_t)l * NH, ln_beta + (size_t)l * NH);
  }
  // readout + two-stage mean pool
  pool1_kernel<<<(NN + 3) / 4, 256, 0, stream>>>(h, W_out, nodeval);
  reduce_pool_kernel<<<(NN + 255) / 256, 256, 0, stream>>>(nodeval, batch, gsum,
                                                           gcnt);
  finalize_kernel<<<1, 64, 0, stream>>>(gsum, gcnt, out);
}

// Round 4
// 517.700 us; speedup vs baseline: 2.9154x; 1.4534x over previous
//
#include <hip/hip_runtime.h>
#include <hip/hip_fp16.h>

#define NN 50000   // nodes
#define NE 800000  // edges
#define NH 128     // hidden
#define NG 32      // graphs
#define NL 4       // layers
#define NB 196     // scan blocks = ceil(NN/256)

typedef __attribute__((ext_vector_type(8))) short bf16x8;
typedef __attribute__((ext_vector_type(4))) float f32x4;

__device__ inline short f2bf(float x) {
  union { float f; unsigned u; } v;
  v.f = x;
  unsigned r = v.u + 0x7FFF + ((v.u >> 16) & 1);
  return (short)(r >> 16);
}
__device__ inline float bf2f(short s) {
  union { unsigned u; float f; } v;
  v.u = ((unsigned)(unsigned short)s) << 16;
  return v.f;
}

// 256-thread block exclusive scan (wave shuffle + 4-wave combine)
__device__ inline int block_exscan(int v) {
  __shared__ int wsum[4];
  int tid = threadIdx.x, wave = tid >> 6, lane = tid & 63;
  int x = v;
#pragma unroll
  for (int off = 1; off < 64; off <<= 1) {
    int y = __shfl_up(x, off, 64);
    if (lane >= off) x += y;
  }
  if (lane == 63) wsum[wave] = x;
  __syncthreads();
  int wp = 0;
  if (wave > 0) wp += wsum[0];
  if (wave > 1) wp += wsum[1];
  if (wave > 2) wp += wsum[2];
  return wp + x - v;
}

// ---------------- split W into bf16 hi/lo ----------------
__global__ __launch_bounds__(256) void prep_split(const float* __restrict__ W,
                                                  short* __restrict__ hi,
                                                  short* __restrict__ lo, int n) {
  int i = blockIdx.x * 256 + threadIdx.x;
  if (i < n) {
    float x = W[i];
    short h = f2bf(x);
    hi[i] = h;
    lo[i] = f2bf(x - bf2f(h));
  }
}

// ---------------- degree histogram over targets ----------------
__global__ __launch_bounds__(256) void hist_kernel(const int* __restrict__ col,
                                                   int* __restrict__ cnt) {
  int e = blockIdx.x * 256 + threadIdx.x;
  if (e < NE) atomicAdd(&cnt[col[e]], 1);
}

// ---------------- scan stage 1: per-block sum of cnt, plus dis ----------------
__global__ __launch_bounds__(256) void scan1_kernel(const int* __restrict__ cnt,
                                                    int* __restrict__ bsum,
                                                    float* __restrict__ dis) {
  int i = blockIdx.x * 256 + threadIdx.x;
  int v = (i < NN) ? cnt[i] : 0;
  if (i < NN) dis[i] = rsqrtf((float)(v + 1));
  int lane = threadIdx.x & 63;
  int s = v;
#pragma unroll
  for (int off = 32; off; off >>= 1) s += __shfl_down(s, off, 64);
  __shared__ int ws[4];
  if (lane == 0) ws[threadIdx.x >> 6] = s;
  __syncthreads();
  if (threadIdx.x == 0) bsum[blockIdx.x] = ws[0] + ws[1] + ws[2] + ws[3];
}

// ---------------- scan stage 2: exclusive scan of NB block sums ----------------
__global__ __launch_bounds__(256) void scan2_kernel(const int* __restrict__ bsum,
                                                    int* __restrict__ ebsum) {
  int tid = threadIdx.x;
  int v = (tid < NB) ? bsum[tid] : 0;
  int ex = block_exscan(v);
  if (tid < NB) ebsum[tid] = ex;
}

// ---------------- scan stage 3: block-local scan + block offset ----------------
__global__ __launch_bounds__(256) void scan3_kernel(const int* __restrict__ cnt,
                                                    const int* __restrict__ ebsum,
                                                    int* __restrict__ offs) {
  int i = blockIdx.x * 256 + threadIdx.x;
  int v = (i < NN) ? cnt[i] : 0;
  int ex = block_exscan(v);
  if (i < NN) offs[i] = ebsum[blockIdx.x] + ex;
}

// ---------------- CSR fill: interleaved (src, weight) pairs ----------------
__global__ __launch_bounds__(256) void fill_kernel(const int* __restrict__ row,
                                                   const int* __restrict__ col,
                                                   const float* __restrict__ dis,
                                                   const int* __restrict__ offs,
                                                   int* __restrict__ fillc,
                                                   int2* __restrict__ csr) {
  int e = blockIdx.x * 256 + threadIdx.x;
  if (e < NE) {
    int d = col[e];
    int s = row[e];
    int pos = offs[d] + atomicAdd(&fillc[d], 1);
    csr[pos] = make_int2(s, __float_as_int(dis[s] * dis[d]));
  }
}

// ---------------- split-bf16 MFMA GEMM: Y[N,128] = X[N,128] @ W[128,128]^T ------
template <bool HALF_OUT>
__global__ __launch_bounds__(256) void gemm_mfma(const float* __restrict__ X,
                                                 const short* __restrict__ Whi,
                                                 const short* __restrict__ Wlo,
                                                 const float* __restrict__ bias,
                                                 float* __restrict__ Yf,
                                                 __half* __restrict__ Yh) {
  int wave = threadIdx.x >> 6, lane = threadIdx.x & 63;
  int quad = lane >> 4, r16 = lane & 15;
  int m0 = blockIdx.x * 64 + wave * 16;
  if (m0 >= NN) return;  // NN % 16 == 0
  int mA = m0 + r16;

  f32x4 acc[8];
#pragma unroll
  for (int t = 0; t < 8; ++t) acc[t] = (f32x4){0.f, 0.f, 0.f, 0.f};

#pragma unroll
  for (int ks = 0; ks < 4; ++ks) {
    int klane = ks * 32 + quad * 8;
    const float* xr = X + (size_t)mA * NH + klane;
    float4 a0 = *(const float4*)xr;
    float4 a1 = *(const float4*)(xr + 4);
    float af[8] = {a0.x, a0.y, a0.z, a0.w, a1.x, a1.y, a1.z, a1.w};
    bf16x8 ahi, alo;
#pragma unroll
    for (int j = 0; j < 8; ++j) {
      short h = f2bf(af[j]);
      ahi[j] = h;
      alo[j] = f2bf(af[j] - bf2f(h));
    }
#pragma unroll
    for (int t = 0; t < 8; ++t) {
      int n = t * 16 + r16;
      bf16x8 bhi = *(const bf16x8*)(Whi + n * NH + klane);
      bf16x8 blo = *(const bf16x8*)(Wlo + n * NH + klane);
      acc[t] = __builtin_amdgcn_mfma_f32_16x16x32_bf16(ahi, bhi, acc[t], 0, 0, 0);
      acc[t] = __builtin_amdgcn_mfma_f32_16x16x32_bf16(alo, bhi, acc[t], 0, 0, 0);
      acc[t] = __builtin_amdgcn_mfma_f32_16x16x32_bf16(ahi, blo, acc[t], 0, 0, 0);
    }
  }
  int mrow = m0 + quad * 4;
#pragma unroll
  for (int t = 0; t < 8; ++t) {
    int col = t * 16 + r16;
    float bb = HALF_OUT ? 0.f : (bias ? bias[col] : 0.f);
#pragma unroll
    for (int r = 0; r < 4; ++r) {
      float v = acc[t][r] + bb;
      if (HALF_OUT)
        Yh[(size_t)(mrow + r) * NH + col] = __float2half(v);
      else
        Yf[(size_t)(mrow + r) * NH + col] = v;
    }
  }
}

// ---------------- fused aggregate + bias + relu + residual + layernorm ----------
// one wave per node; t fp16; edge loop unrolled x8/x4 for MLP (8 gathers in flight)
__global__ __launch_bounds__(256) void aggregate_kernel(
    const __half* __restrict__ t, float* __restrict__ h,
    const float* __restrict__ dis, const int* __restrict__ offs,
    const int* __restrict__ cnt, const int2* __restrict__ csr,
    const float* __restrict__ bias, const float* __restrict__ gamma,
    const float* __restrict__ beta) {
  int node = blockIdx.x * 4 + (threadIdx.x >> 6);
  int lane = threadIdx.x & 63;
  if (node >= NN) return;
  const __half2* t2 = (const __half2*)t;
  float2* h2 = (float2*)h;
  float dii = dis[node];
  float sl = dii * dii;  // self-loop norm
  float2 tv = __half22float2(t2[(size_t)node * 64 + lane]);
  float a0 = tv.x * sl, a1 = tv.y * sl;
  int s0 = offs[node];
  int e = cnt[node];
  int j = 0;
  for (; j + 8 <= e; j += 8) {
    int2 p[8];
#pragma unroll
    for (int u = 0; u < 8; ++u) p[u] = csr[s0 + j + u];
    float2 m[8];
#pragma unroll
    for (int u = 0; u < 8; ++u)
      m[u] = __half22float2(t2[(size_t)p[u].x * 64 + lane]);
#pragma unroll
    for (int u = 0; u < 8; ++u) {
      float w = __int_as_float(p[u].y);
      a0 += m[u].x * w;
      a1 += m[u].y * w;
    }
  }
  for (; j + 4 <= e; j += 4) {
    int2 p[4];
#pragma unroll
    for (int u = 0; u < 4; ++u) p[u] = csr[s0 + j + u];
    float2 m[4];
#pragma unroll
    for (int u = 0; u < 4; ++u)
      m[u] = __half22float2(t2[(size_t)p[u].x * 64 + lane]);
#pragma unroll
    for (int u = 0; u < 4; ++u) {
      float w = __int_as_float(p[u].y);
      a0 += m[u].x * w;
      a1 += m[u].y * w;
    }
  }
  for (; j < e; ++j) {
    int2 p = csr[s0 + j];
    float w = __int_as_float(p.y);
    float2 m = __half22float2(t2[(size_t)p.x * 64 + lane]);
    a0 += m.x * w;
    a1 += m.y * w;
  }
  float2 bv = ((const float2*)bias)[lane];
  a0 = fmaxf(a0 + bv.x, 0.f);
  a1 = fmaxf(a1 + bv.y, 0.f);
  float2 hv = h2[(size_t)node * 64 + lane];
  float v0 = hv.x + a0, v1 = hv.y + a1;
  float s = v0 + v1, s2 = v0 * v0 + v1 * v1;
#pragma unroll
  for (int off = 32; off; off >>= 1) {
    s += __shfl_down(s, off, 64);
    s2 += __shfl_down(s2, off, 64);
  }
  s = __shfl(s, 0, 64);
  s2 = __shfl(s2, 0, 64);
  float mean = s * (1.f / 128.f);
  float var = fmaxf(s2 * (1.f / 128.f) - mean * mean, 0.f);
  float inv = rsqrtf(var + 1e-5f);
  float2 gv = ((const float2*)gamma)[lane];
  float2 bt = ((const float2*)beta)[lane];
  float2 o;
  o.x = (v0 - mean) * inv * gv.x + bt.x;
  o.y = (v1 - mean) * inv * gv.y + bt.y;
  h2[(size_t)node * 64 + lane] = o;
}

// ---------------- stage 1: per-node dot with W_out ----------------
__global__ __launch_bounds__(256) void pool1_kernel(const float* __restrict__ h,
                                                    const float* __restrict__ Wout,
                                                    float* __restrict__ nodeval) {
  int node = blockIdx.x * 4 + (threadIdx.x >> 6);
  int lane = threadIdx.x & 63;
  if (node >= NN) return;
  const float2* h2 = (const float2*)h;
  const float2* w2 = (const float2*)Wout;
  float2 hv = h2[(size_t)node * 64 + lane];
  float2 wv = w2[lane];
  float s = hv.x * wv.x + hv.y * wv.y;
#pragma unroll
  for (int off = 32; off; off >>= 1) s += __shfl_down(s, off, 64);
  if (lane == 0) nodeval[node] = s;
}

// ---------------- stage 2: LDS-binned segment reduction ----------------
__global__ __launch_bounds__(256) void reduce_pool_kernel(
    const float* __restrict__ nodeval, const int* __restrict__ batch,
    float* __restrict__ gsum, int* __restrict__ gcnt) {
  __shared__ float bins[NG];
  __shared__ int cbins[NG];
  int tid = threadIdx.x;
  if (tid < NG) {
    bins[tid] = 0.f;
    cbins[tid] = 0;
  }
  __syncthreads();
  int i = blockIdx.x * 256 + tid;
  if (i < NN) {
    int g = batch[i];
    atomicAdd(&bins[g], nodeval[i]);
    atomicAdd(&cbins[g], 1);
  }
  __syncthreads();
  if (tid < NG) {
    if (cbins[tid]) {
      atomicAdd(&gsum[tid], bins[tid]);
      atomicAdd(&gcnt[tid], cbins[tid]);
    }
  }
}

__global__ void finalize_kernel(const float* __restrict__ gsum,
                                const int* __restrict__ gcnt,
                                float* __restrict__ out) {
  int g = threadIdx.x;
  if (g < NG) out[g] = gsum[g] / fmaxf((float)gcnt[g], 1.0f);
}

extern "C" void kernel_launch(void* const* d_in, const int* in_sizes, int n_in,
                              void* d_out, int out_size, void* d_ws, size_t ws_size,
                              hipStream_t stream) {
  const float* x = (const float*)d_in[0];
  const int* eidx = (const int*)d_in[1];
  const int* batch = (const int*)d_in[2];
  const float* W_emb = (const float*)d_in[3];
  const float* b_emb = (const float*)d_in[4];
  const float* W_layers = (const float*)d_in[5];
  const float* b_layers = (const float*)d_in[6];
  const float* ln_gamma = (const float*)d_in[7];
  const float* ln_beta = (const float*)d_in[8];
  const float* W_out = (const float*)d_in[9];
  float* out = (float*)d_out;

  char* ws = (char*)d_ws;
  __half* t = (__half*)ws;      ws += (size_t)NN * NH * 2;
  float* h = (float*)ws;        ws += (size_t)NN * NH * 4;
  short* Whi = (short*)ws;      ws += (size_t)5 * NH * NH * 2;
  short* Wlo = (short*)ws;      ws += (size_t)5 * NH * NH * 2;
  float* dis = (float*)ws;      ws += (size_t)NN * 4;
  int2* csr = (int2*)ws;        ws += (size_t)NE * 8;
  int* offs = (int*)ws;         ws += (size_t)NN * 4;
  float* nodeval = (float*)ws;  ws += (size_t)NN * 4;
  int* bsum = (int*)ws;         ws += (size_t)NB * 4;
  int* ebsum = (int*)ws;        ws += (size_t)NB * 4;
  char* zero_base = ws;
  int* cnt = (int*)ws;          ws += (size_t)NN * 4;
  int* fillc = (int*)ws;        ws += (size_t)NN * 4;
  float* gsum = (float*)ws;     ws += (size_t)NG * 4;
  int* gcnt = (int*)ws;         ws += (size_t)NG * 4;
  size_t zero_bytes = (size_t)(ws - zero_base);
  hipMemsetAsync(zero_base, 0, zero_bytes, stream);

  const int* erow = eidx;        // edge_index[0] = sources
  const int* ecol = eidx + NE;   // edge_index[1] = targets

  prep_split<<<(NH * NH + 255) / 256, 256, 0, stream>>>(W_emb, Whi, Wlo, NH * NH);
  prep_split<<<(NL * NH * NH + 255) / 256, 256, 0, stream>>>(
      W_layers, Whi + NH * NH, Wlo + NH * NH, NL * NH * NH);

  hist_kernel<<<(NE + 255) / 256, 256, 0, stream>>>(ecol, cnt);
  scan1_kernel<<<NB, 256, 0, stream>>>(cnt, bsum, dis);
  scan2_kernel<<<1, 256, 0, stream>>>(bsum, ebsum);
  scan3_kernel<<<NB, 256, 0, stream>>>(cnt, ebsum, offs);
  fill_kernel<<<(NE + 255) / 256, 256, 0, stream>>>(erow, ecol, dis, offs, fillc,
                                                    csr);
  int gblk = (NN + 63) / 64;
  gemm_mfma<false><<<gblk, 256, 0, stream>>>(x, Whi, Wlo, b_emb, h, nullptr);
  for (int l = 0; l < NL; ++l) {
    gemm_mfma<true><<<gblk, 256, 0, stream>>>(
        h, Whi + (size_t)(l + 1) * NH * NH, Wlo + (size_t)(l + 1) * NH * NH,
        nullptr, nullptr, t);
    aggregate_kernel<<<(NN + 3) / 4, 256, 0, stream>>>(
        t, h, dis, offs, cnt, csr, b_layers + (size_t)l * NH,
        ln_gamma + (size_t)l * NH, ln_beta + (size_t)l * NH);
  }
  pool1_kernel<<<(NN + 3) / 4, 256, 0, stream>>>(h, W_out, nodeval);
  reduce_pool_kernel<<<(NN + 255) / 256, 256, 0, stream>>>(nodeval, batch, gsum,
                                                           gcnt);
  finalize_kernel<<<1, 64, 0, stream>>>(gsum, gcnt, out);
}

// Round 5
// 495.614 us; speedup vs baseline: 3.0453x; 1.0446x over previous
//
#include <hip/hip_runtime.h>
#include <hip/hip_fp16.h>

#define NN 50000   // nodes
#define NE 800000  // edges
#define NH 128     // hidden
#define NG 32      // graphs
#define NL 4       // layers
#define NB 196     // scan blocks = ceil(NN/256)

typedef __attribute__((ext_vector_type(8))) short bf16x8;
typedef __attribute__((ext_vector_type(4))) float f32x4;

__device__ inline short f2bf(float x) {
  union { float f; unsigned u; } v;
  v.f = x;
  unsigned r = v.u + 0x7FFF + ((v.u >> 16) & 1);
  return (short)(r >> 16);
}
__device__ inline float bf2f(short s) {
  union { unsigned u; float f; } v;
  v.u = ((unsigned)(unsigned short)s) << 16;
  return v.f;
}

// 256-thread block exclusive scan (wave shuffle + 4-wave combine)
__device__ inline int block_exscan(int v) {
  __shared__ int wsum[4];
  int tid = threadIdx.x, wave = tid >> 6, lane = tid & 63;
  int x = v;
#pragma unroll
  for (int off = 1; off < 64; off <<= 1) {
    int y = __shfl_up(x, off, 64);
    if (lane >= off) x += y;
  }
  if (lane == 63) wsum[wave] = x;
  __syncthreads();
  int wp = 0;
  if (wave > 0) wp += wsum[0];
  if (wave > 1) wp += wsum[1];
  if (wave > 2) wp += wsum[2];
  return wp + x - v;
}

// ---------------- split W into bf16 hi/lo ----------------
__global__ __launch_bounds__(256) void prep_split(const float* __restrict__ W,
                                                  short* __restrict__ hi,
                                                  short* __restrict__ lo, int n) {
  int i = blockIdx.x * 256 + threadIdx.x;
  if (i < n) {
    float x = W[i];
    short h = f2bf(x);
    hi[i] = h;
    lo[i] = f2bf(x - bf2f(h));
  }
}

// ---------------- degree histogram over targets; atomic return = edge rank ------
__global__ __launch_bounds__(256) void hist_kernel(const int* __restrict__ col,
                                                   int* __restrict__ cnt,
                                                   int* __restrict__ rank) {
  int e = blockIdx.x * 256 + threadIdx.x;
  if (e < NE) rank[e] = atomicAdd(&cnt[col[e]], 1);
}

// ---------------- scan stage 1: per-block sum of cnt, plus dis ----------------
__global__ __launch_bounds__(256) void scan1_kernel(const int* __restrict__ cnt,
                                                    int* __restrict__ bsum,
                                                    float* __restrict__ dis) {
  int i = blockIdx.x * 256 + threadIdx.x;
  int v = (i < NN) ? cnt[i] : 0;
  if (i < NN) dis[i] = rsqrtf((float)(v + 1));
  int lane = threadIdx.x & 63;
  int s = v;
#pragma unroll
  for (int off = 32; off; off >>= 1) s += __shfl_down(s, off, 64);
  __shared__ int ws[4];
  if (lane == 0) ws[threadIdx.x >> 6] = s;
  __syncthreads();
  if (threadIdx.x == 0) bsum[blockIdx.x] = ws[0] + ws[1] + ws[2] + ws[3];
}

// ---------------- scan stage 2: exclusive scan of NB block sums ----------------
__global__ __launch_bounds__(256) void scan2_kernel(const int* __restrict__ bsum,
                                                    int* __restrict__ ebsum) {
  int tid = threadIdx.x;
  int v = (tid < NB) ? bsum[tid] : 0;
  int ex = block_exscan(v);
  if (tid < NB) ebsum[tid] = ex;
}

// ---------------- scan stage 3: block-local scan + block offset ----------------
__global__ __launch_bounds__(256) void scan3_kernel(const int* __restrict__ cnt,
                                                    const int* __restrict__ ebsum,
                                                    int* __restrict__ offs) {
  int i = blockIdx.x * 256 + threadIdx.x;
  int v = (i < NN) ? cnt[i] : 0;
  int ex = block_exscan(v);
  if (i < NN) offs[i] = ebsum[blockIdx.x] + ex;
}

// ---------------- CSR fill (no atomics: rank precomputed by hist) ----------------
__global__ __launch_bounds__(256) void fill_kernel(const int* __restrict__ row,
                                                   const int* __restrict__ col,
                                                   const int* __restrict__ rank,
                                                   const float* __restrict__ dis,
                                                   const int* __restrict__ offs,
                                                   int2* __restrict__ csr) {
  int e = blockIdx.x * 256 + threadIdx.x;
  if (e < NE) {
    int d = col[e];
    int s = row[e];
    int pos = offs[d] + rank[e];
    csr[pos] = make_int2(s, __float_as_int(dis[s] * dis[d]));
  }
}

// ---------------- split-bf16 MFMA GEMM: Y[N,128] = X[N,128] @ W[128,128]^T ------
template <bool HALF_OUT>
__global__ __launch_bounds__(256) void gemm_mfma(const float* __restrict__ X,
                                                 const short* __restrict__ Whi,
                                                 const short* __restrict__ Wlo,
                                                 const float* __restrict__ bias,
                                                 float* __restrict__ Yf,
                                                 __half* __restrict__ Yh) {
  int wave = threadIdx.x >> 6, lane = threadIdx.x & 63;
  int quad = lane >> 4, r16 = lane & 15;
  int m0 = blockIdx.x * 64 + wave * 16;
  if (m0 >= NN) return;  // NN % 16 == 0
  int mA = m0 + r16;

  f32x4 acc[8];
#pragma unroll
  for (int t = 0; t < 8; ++t) acc[t] = (f32x4){0.f, 0.f, 0.f, 0.f};

#pragma unroll
  for (int ks = 0; ks < 4; ++ks) {
    int klane = ks * 32 + quad * 8;
    const float* xr = X + (size_t)mA * NH + klane;
    float4 a0 = *(const float4*)xr;
    float4 a1 = *(const float4*)(xr + 4);
    float af[8] = {a0.x, a0.y, a0.z, a0.w, a1.x, a1.y, a1.z, a1.w};
    bf16x8 ahi, alo;
#pragma unroll
    for (int j = 0; j < 8; ++j) {
      short h = f2bf(af[j]);
      ahi[j] = h;
      alo[j] = f2bf(af[j] - bf2f(h));
    }
#pragma unroll
    for (int t = 0; t < 8; ++t) {
      int n = t * 16 + r16;
      bf16x8 bhi = *(const bf16x8*)(Whi + n * NH + klane);
      bf16x8 blo = *(const bf16x8*)(Wlo + n * NH + klane);
      acc[t] = __builtin_amdgcn_mfma_f32_16x16x32_bf16(ahi, bhi, acc[t], 0, 0, 0);
      acc[t] = __builtin_amdgcn_mfma_f32_16x16x32_bf16(alo, bhi, acc[t], 0, 0, 0);
      acc[t] = __builtin_amdgcn_mfma_f32_16x16x32_bf16(ahi, blo, acc[t], 0, 0, 0);
    }
  }
  int mrow = m0 + quad * 4;
#pragma unroll
  for (int t = 0; t < 8; ++t) {
    int col = t * 16 + r16;
    float bb = HALF_OUT ? 0.f : (bias ? bias[col] : 0.f);
#pragma unroll
    for (int r = 0; r < 4; ++r) {
      float v = acc[t][r] + bb;
      if (HALF_OUT)
        Yh[(size_t)(mrow + r) * NH + col] = __float2half(v);
      else
        Yf[(size_t)(mrow + r) * NH + col] = v;
    }
  }
}

// ---------------- fused aggregate + bias + relu + residual + layernorm ----------
// one wave per node; t fp16; edge loop tiers 16/8/4/1 keep gathers in flight.
// When Wout != nullptr (last layer) also emits nodeval = h_new . Wout (fuses pool1)
__global__ __launch_bounds__(256) void aggregate_kernel(
    const __half* __restrict__ t, float* __restrict__ h,
    const float* __restrict__ dis, const int* __restrict__ offs,
    const int* __restrict__ cnt, const int2* __restrict__ csr,
    const float* __restrict__ bias, const float* __restrict__ gamma,
    const float* __restrict__ beta, const float* __restrict__ Wout,
    float* __restrict__ nodeval) {
  int node = blockIdx.x * 4 + (threadIdx.x >> 6);
  int lane = threadIdx.x & 63;
  if (node >= NN) return;
  const __half2* t2 = (const __half2*)t;
  float2* h2 = (float2*)h;
  float dii = dis[node];
  float sl = dii * dii;  // self-loop norm
  float2 tv = __half22float2(t2[(size_t)node * 64 + lane]);
  float a0 = tv.x * sl, a1 = tv.y * sl;
  int s0 = offs[node];
  int e = cnt[node];
  int j = 0;
  for (; j + 16 <= e; j += 16) {
    int2 p[16];
#pragma unroll
    for (int u = 0; u < 16; ++u) p[u] = csr[s0 + j + u];
    float2 m[16];
#pragma unroll
    for (int u = 0; u < 16; ++u)
      m[u] = __half22float2(t2[(size_t)p[u].x * 64 + lane]);
#pragma unroll
    for (int u = 0; u < 16; ++u) {
      float w = __int_as_float(p[u].y);
      a0 += m[u].x * w;
      a1 += m[u].y * w;
    }
  }
  for (; j + 8 <= e; j += 8) {
    int2 p[8];
#pragma unroll
    for (int u = 0; u < 8; ++u) p[u] = csr[s0 + j + u];
    float2 m[8];
#pragma unroll
    for (int u = 0; u < 8; ++u)
      m[u] = __half22float2(t2[(size_t)p[u].x * 64 + lane]);
#pragma unroll
    for (int u = 0; u < 8; ++u) {
      float w = __int_as_float(p[u].y);
      a0 += m[u].x * w;
      a1 += m[u].y * w;
    }
  }
  for (; j + 4 <= e; j += 4) {
    int2 p[4];
#pragma unroll
    for (int u = 0; u < 4; ++u) p[u] = csr[s0 + j + u];
    float2 m[4];
#pragma unroll
    for (int u = 0; u < 4; ++u)
      m[u] = __half22float2(t2[(size_t)p[u].x * 64 + lane]);
#pragma unroll
    for (int u = 0; u < 4; ++u) {
      float w = __int_as_float(p[u].y);
      a0 += m[u].x * w;
      a1 += m[u].y * w;
    }
  }
  for (; j < e; ++j) {
    int2 p = csr[s0 + j];
    float w = __int_as_float(p.y);
    float2 m = __half22float2(t2[(size_t)p.x * 64 + lane]);
    a0 += m.x * w;
    a1 += m.y * w;
  }
  float2 bv = ((const float2*)bias)[lane];
  a0 = fmaxf(a0 + bv.x, 0.f);
  a1 = fmaxf(a1 + bv.y, 0.f);
  float2 hv = h2[(size_t)node * 64 + lane];
  float v0 = hv.x + a0, v1 = hv.y + a1;
  float s = v0 + v1, s2 = v0 * v0 + v1 * v1;
#pragma unroll
  for (int off = 32; off; off >>= 1) {
    s += __shfl_down(s, off, 64);
    s2 += __shfl_down(s2, off, 64);
  }
  s = __shfl(s, 0, 64);
  s2 = __shfl(s2, 0, 64);
  float mean = s * (1.f / 128.f);
  float var = fmaxf(s2 * (1.f / 128.f) - mean * mean, 0.f);
  float inv = rsqrtf(var + 1e-5f);
  float2 gv = ((const float2*)gamma)[lane];
  float2 bt = ((const float2*)beta)[lane];
  float2 o;
  o.x = (v0 - mean) * inv * gv.x + bt.x;
  o.y = (v1 - mean) * inv * gv.y + bt.y;
  h2[(size_t)node * 64 + lane] = o;
  if (Wout) {  // fused readout dot (last layer)
    float2 wv = ((const float2*)Wout)[lane];
    float d = o.x * wv.x + o.y * wv.y;
#pragma unroll
    for (int off = 32; off; off >>= 1) d += __shfl_down(d, off, 64);
    if (lane == 0) nodeval[node] = d;
  }
}

// ---------------- stage 2: LDS-binned segment reduction ----------------
__global__ __launch_bounds__(256) void reduce_pool_kernel(
    const float* __restrict__ nodeval, const int* __restrict__ batch,
    float* __restrict__ gsum, int* __restrict__ gcnt) {
  __shared__ float bins[NG];
  __shared__ int cbins[NG];
  int tid = threadIdx.x;
  if (tid < NG) {
    bins[tid] = 0.f;
    cbins[tid] = 0;
  }
  __syncthreads();
  int i = blockIdx.x * 256 + tid;
  if (i < NN) {
    int g = batch[i];
    atomicAdd(&bins[g], nodeval[i]);
    atomicAdd(&cbins[g], 1);
  }
  __syncthreads();
  if (tid < NG) {
    if (cbins[tid]) {
      atomicAdd(&gsum[tid], bins[tid]);
      atomicAdd(&gcnt[tid], cbins[tid]);
    }
  }
}

__global__ void finalize_kernel(const float* __restrict__ gsum,
                                const int* __restrict__ gcnt,
                                float* __restrict__ out) {
  int g = threadIdx.x;
  if (g < NG) out[g] = gsum[g] / fmaxf((float)gcnt[g], 1.0f);
}

extern "C" void kernel_launch(void* const* d_in, const int* in_sizes, int n_in,
                              void* d_out, int out_size, void* d_ws, size_t ws_size,
                              hipStream_t stream) {
  const float* x = (const float*)d_in[0];
  const int* eidx = (const int*)d_in[1];
  const int* batch = (const int*)d_in[2];
  const float* W_emb = (const float*)d_in[3];
  const float* b_emb = (const float*)d_in[4];
  const float* W_layers = (const float*)d_in[5];
  const float* b_layers = (const float*)d_in[6];
  const float* ln_gamma = (const float*)d_in[7];
  const float* ln_beta = (const float*)d_in[8];
  const float* W_out = (const float*)d_in[9];
  float* out = (float*)d_out;

  char* ws = (char*)d_ws;
  __half* t = (__half*)ws;      ws += (size_t)NN * NH * 2;
  float* h = (float*)ws;        ws += (size_t)NN * NH * 4;
  short* Whi = (short*)ws;      ws += (size_t)5 * NH * NH * 2;
  short* Wlo = (short*)ws;      ws += (size_t)5 * NH * NH * 2;
  float* dis = (float*)ws;      ws += (size_t)NN * 4;
  int2* csr = (int2*)ws;        ws += (size_t)NE * 8;
  int* rank = (int*)ws;         ws += (size_t)NE * 4;
  int* offs = (int*)ws;         ws += (size_t)NN * 4;
  float* nodeval = (float*)ws;  ws += (size_t)NN * 4;
  int* bsum = (int*)ws;         ws += (size_t)NB * 4;
  int* ebsum = (int*)ws;        ws += (size_t)NB * 4;
  char* zero_base = ws;
  int* cnt = (int*)ws;          ws += (size_t)NN * 4;
  float* gsum = (float*)ws;     ws += (size_t)NG * 4;
  int* gcnt = (int*)ws;         ws += (size_t)NG * 4;
  size_t zero_bytes = (size_t)(ws - zero_base);
  hipMemsetAsync(zero_base, 0, zero_bytes, stream);

  const int* erow = eidx;        // edge_index[0] = sources
  const int* ecol = eidx + NE;   // edge_index[1] = targets

  prep_split<<<(NH * NH + 255) / 256, 256, 0, stream>>>(W_emb, Whi, Wlo, NH * NH);
  prep_split<<<(NL * NH * NH + 255) / 256, 256, 0, stream>>>(
      W_layers, Whi + NH * NH, Wlo + NH * NH, NL * NH * NH);

  hist_kernel<<<(NE + 255) / 256, 256, 0, stream>>>(ecol, cnt, rank);
  scan1_kernel<<<NB, 256, 0, stream>>>(cnt, bsum, dis);
  scan2_kernel<<<1, 256, 0, stream>>>(bsum, ebsum);
  scan3_kernel<<<NB, 256, 0, stream>>>(cnt, ebsum, offs);
  fill_kernel<<<(NE + 255) / 256, 256, 0, stream>>>(erow, ecol, rank, dis, offs,
                                                    csr);
  int gblk = (NN + 63) / 64;
  gemm_mfma<false><<<gblk, 256, 0, stream>>>(x, Whi, Wlo, b_emb, h, nullptr);
  for (int l = 0; l < NL; ++l) {
    gemm_mfma<true><<<gblk, 256, 0, stream>>>(
        h, Whi + (size_t)(l + 1) * NH * NH, Wlo + (size_t)(l + 1) * NH * NH,
        nullptr, nullptr, t);
    bool last = (l == NL - 1);
    aggregate_kernel<<<(NN + 3) / 4, 256, 0, stream>>>(
        t, h, dis, offs, cnt, csr, b_layers + (size_t)l * NH,
        ln_gamma + (size_t)l * NH, ln_beta + (size_t)l * NH,
        last ? W_out : nullptr, nodeval);
  }
  reduce_pool_kernel<<<(NN + 255) / 256, 256, 0, stream>>>(nodeval, batch, gsum,
                                                           gcnt);
  finalize_kernel<<<1, 64, 0, stream>>>(gsum, gcnt, out);
}

// Round 6
// 411.118 us; speedup vs baseline: 3.6712x; 1.2055x over previous
//
#include <hip/hip_runtime.h>
#include <hip/hip_fp16.h>

#define NN 50000   // nodes
#define NE 800000  // edges
#define NH 128     // hidden
#define NG 32      // graphs
#define NL 4       // layers
#define NB 196     // scan blocks = ceil(NN/256)
#define WSLOT (NH * NH)  // 16384 elements per weight slot

typedef __attribute__((ext_vector_type(8))) short bf16x8;
typedef __attribute__((ext_vector_type(4))) float f32x4;

__device__ inline short f2bf(float x) {
  union { float f; unsigned u; } v;
  v.f = x;
  unsigned r = v.u + 0x7FFF + ((v.u >> 16) & 1);
  return (short)(r >> 16);
}
__device__ inline float bf2f(short s) {
  union { unsigned u; float f; } v;
  v.u = ((unsigned)(unsigned short)s) << 16;
  return v.f;
}

// 256-thread block exclusive scan (wave shuffle + 4-wave combine)
__device__ inline int block_exscan(int v) {
  __shared__ int wsum[4];
  int tid = threadIdx.x, wave = tid >> 6, lane = tid & 63;
  int x = v;
#pragma unroll
  for (int off = 1; off < 64; off <<= 1) {
    int y = __shfl_up(x, off, 64);
    if (lane >= off) x += y;
  }
  if (lane == 63) wsum[wave] = x;
  __syncthreads();
  int wp = 0;
  if (wave > 0) wp += wsum[0];
  if (wave > 1) wp += wsum[1];
  if (wave > 2) wp += wsum[2];
  return wp + x - v;
}

// ---------------- split W into bf16 hi/lo, swizzled into MFMA fragment order ----
// frag layout: idx = ((ks*8 + t)*64 + lane)*8 + j  <->  W[n][k],
//   n = t*16 + (lane&15), k = ks*32 + (lane>>4)*8 + j
// so gemm's per-(ks,t) wave load is 64 lanes x 16B fully coalesced.
__global__ __launch_bounds__(256) void prep_swizzle(const float* __restrict__ W_emb,
                                                    const float* __restrict__ W_layers,
                                                    short* __restrict__ hi,
                                                    short* __restrict__ lo) {
  int i = blockIdx.x * 256 + threadIdx.x;
  if (i >= 5 * WSLOT) return;
  int slot = i >> 14, f = i & (WSLOT - 1);
  int j = f & 7, lane = (f >> 3) & 63, tt = (f >> 9) & 7, ks = f >> 12;
  int n = tt * 16 + (lane & 15);
  int k = ks * 32 + ((lane >> 4) & 3) * 8 + j;
  const float* W = slot ? (W_layers + (size_t)(slot - 1) * WSLOT) : W_emb;
  float x = W[n * NH + k];
  short hh = f2bf(x);
  hi[i] = hh;
  lo[i] = f2bf(x - bf2f(hh));
}

// ---------------- degree histogram over targets; atomic return = edge rank ------
__global__ __launch_bounds__(256) void hist_kernel(const int* __restrict__ col,
                                                   int* __restrict__ cnt,
                                                   int* __restrict__ rank) {
  int e = blockIdx.x * 256 + threadIdx.x;
  if (e < NE) rank[e] = atomicAdd(&cnt[col[e]], 1);
}

// ---------------- scan stage 1: per-block sum of cnt, plus dis ----------------
__global__ __launch_bounds__(256) void scan1_kernel(const int* __restrict__ cnt,
                                                    int* __restrict__ bsum,
                                                    float* __restrict__ dis) {
  int i = blockIdx.x * 256 + threadIdx.x;
  int v = (i < NN) ? cnt[i] : 0;
  if (i < NN) dis[i] = rsqrtf((float)(v + 1));
  int lane = threadIdx.x & 63;
  int s = v;
#pragma unroll
  for (int off = 32; off; off >>= 1) s += __shfl_down(s, off, 64);
  __shared__ int ws[4];
  if (lane == 0) ws[threadIdx.x >> 6] = s;
  __syncthreads();
  if (threadIdx.x == 0) bsum[blockIdx.x] = ws[0] + ws[1] + ws[2] + ws[3];
}

// ---------------- scan stage 2: exclusive scan of NB block sums ----------------
__global__ __launch_bounds__(256) void scan2_kernel(const int* __restrict__ bsum,
                                                    int* __restrict__ ebsum) {
  int tid = threadIdx.x;
  int v = (tid < NB) ? bsum[tid] : 0;
  int ex = block_exscan(v);
  if (tid < NB) ebsum[tid] = ex;
}

// ---------------- scan stage 3: block-local scan + block offset ----------------
__global__ __launch_bounds__(256) void scan3_kernel(const int* __restrict__ cnt,
                                                    const int* __restrict__ ebsum,
                                                    int* __restrict__ offs) {
  int i = blockIdx.x * 256 + threadIdx.x;
  int v = (i < NN) ? cnt[i] : 0;
  int ex = block_exscan(v);
  if (i < NN) offs[i] = ebsum[blockIdx.x] + ex;
}

// ---------------- CSR fill (no atomics: rank precomputed by hist) ----------------
__global__ __launch_bounds__(256) void fill_kernel(const int* __restrict__ row,
                                                   const int* __restrict__ col,
                                                   const int* __restrict__ rank,
                                                   const float* __restrict__ dis,
                                                   const int* __restrict__ offs,
                                                   int2* __restrict__ csr) {
  int e = blockIdx.x * 256 + threadIdx.x;
  if (e < NE) {
    int d = col[e];
    int s = row[e];
    int pos = offs[d] + rank[e];
    csr[pos] = make_int2(s, __float_as_int(dis[s] * dis[d]));
  }
}

// ---------------- split-bf16 MFMA GEMM: Y[N,128] = X[N,128] @ W[128,128]^T ------
// B from pre-swizzled fragment arrays (coalesced 1KB wave loads).
template <bool HALF_OUT>
__global__ __launch_bounds__(256) void gemm_mfma(const float* __restrict__ X,
                                                 const short* __restrict__ Whi,
                                                 const short* __restrict__ Wlo,
                                                 const float* __restrict__ bias,
                                                 float* __restrict__ Yf,
                                                 __half* __restrict__ Yh) {
  int wave = threadIdx.x >> 6, lane = threadIdx.x & 63;
  int quad = lane >> 4, r16 = lane & 15;
  int m0 = blockIdx.x * 64 + wave * 16;
  if (m0 >= NN) return;  // NN % 16 == 0
  int mA = m0 + r16;

  f32x4 acc[8];
#pragma unroll
  for (int t = 0; t < 8; ++t) acc[t] = (f32x4){0.f, 0.f, 0.f, 0.f};

#pragma unroll
  for (int ks = 0; ks < 4; ++ks) {
    int klane = ks * 32 + quad * 8;
    const float* xr = X + (size_t)mA * NH + klane;
    float4 a0 = *(const float4*)xr;
    float4 a1 = *(const float4*)(xr + 4);
    float af[8] = {a0.x, a0.y, a0.z, a0.w, a1.x, a1.y, a1.z, a1.w};
    bf16x8 ahi, alo;
#pragma unroll
    for (int j = 0; j < 8; ++j) {
      short h = f2bf(af[j]);
      ahi[j] = h;
      alo[j] = f2bf(af[j] - bf2f(h));
    }
#pragma unroll
    for (int t = 0; t < 8; ++t) {
      int fidx = ((ks * 8 + t) * 64 + lane) << 3;
      bf16x8 bhi = *(const bf16x8*)(Whi + fidx);
      bf16x8 blo = *(const bf16x8*)(Wlo + fidx);
      acc[t] = __builtin_amdgcn_mfma_f32_16x16x32_bf16(ahi, bhi, acc[t], 0, 0, 0);
      acc[t] = __builtin_amdgcn_mfma_f32_16x16x32_bf16(alo, bhi, acc[t], 0, 0, 0);
      acc[t] = __builtin_amdgcn_mfma_f32_16x16x32_bf16(ahi, blo, acc[t], 0, 0, 0);
    }
  }
  int mrow = m0 + quad * 4;
#pragma unroll
  for (int t = 0; t < 8; ++t) {
    int col = t * 16 + r16;
    float bb = HALF_OUT ? 0.f : (bias ? bias[col] : 0.f);
#pragma unroll
    for (int r = 0; r < 4; ++r) {
      float v = acc[t][r] + bb;
      if (HALF_OUT)
        Yh[(size_t)(mrow + r) * NH + col] = __float2half(v);
      else
        Yf[(size_t)(mrow + r) * NH + col] = v;
    }
  }
}

// ---------------- fused aggregate + bias + relu + residual + layernorm ----------
// one wave per node; 4 channels/lane x 32 lanes per edge -> 2 edges per
// wave-instruction (halves vmem inst count vs 1-edge-per-instruction).
// When Wout != nullptr (last layer) also emits nodeval = h_new . Wout
__global__ __launch_bounds__(256) void aggregate_kernel(
    const __half* __restrict__ t, float* __restrict__ h,
    const float* __restrict__ dis, const int* __restrict__ offs,
    const int* __restrict__ cnt, const int2* __restrict__ csr,
    const float* __restrict__ bias, const float* __restrict__ gamma,
    const float* __restrict__ beta, const float* __restrict__ Wout,
    float* __restrict__ nodeval) {
  int node = blockIdx.x * 4 + (threadIdx.x >> 6);
  int lane = threadIdx.x & 63;
  if (node >= NN) return;
  int hf = lane >> 5;        // which edge of the pair
  int c4 = (lane & 31) << 2; // channel base (4 channels per lane)
  float dii = dis[node];
  float sl = dii * dii;      // self-loop norm
  float4 a = make_float4(0.f, 0.f, 0.f, 0.f);
  if (hf == 0) {  // self loop handled by half 0
    float2 raw = *(const float2*)(t + (size_t)node * NH + c4);
    float2 f01 = __half22float2(*(__half2*)&raw.x);
    float2 f23 = __half22float2(*(__half2*)&raw.y);
    a.x = f01.x * sl; a.y = f01.y * sl; a.z = f23.x * sl; a.w = f23.y * sl;
  }
  int s0 = offs[node];
  int e = cnt[node];
  int j = 0;
  for (; j + 16 <= e; j += 16) {  // 8 pairs
    int2 p[8];
    float2 raw[8];
#pragma unroll
    for (int u = 0; u < 8; ++u) p[u] = csr[s0 + j + 2 * u + hf];
#pragma unroll
    for (int u = 0; u < 8; ++u)
      raw[u] = *(const float2*)(t + (size_t)p[u].x * NH + c4);
#pragma unroll
    for (int u = 0; u < 8; ++u) {
      float w = __int_as_float(p[u].y);
      float2 f01 = __half22float2(*(__half2*)&raw[u].x);
      float2 f23 = __half22float2(*(__half2*)&raw[u].y);
      a.x += f01.x * w; a.y += f01.y * w; a.z += f23.x * w; a.w += f23.y * w;
    }
  }
  for (; j + 8 <= e; j += 8) {  // 4 pairs
    int2 p[4];
    float2 raw[4];
#pragma unroll
    for (int u = 0; u < 4; ++u) p[u] = csr[s0 + j + 2 * u + hf];
#pragma unroll
    for (int u = 0; u < 4; ++u)
      raw[u] = *(const float2*)(t + (size_t)p[u].x * NH + c4);
#pragma unroll
    for (int u = 0; u < 4; ++u) {
      float w = __int_as_float(p[u].y);
      float2 f01 = __half22float2(*(__half2*)&raw[u].x);
      float2 f23 = __half22float2(*(__half2*)&raw[u].y);
      a.x += f01.x * w; a.y += f01.y * w; a.z += f23.x * w; a.w += f23.y * w;
    }
  }
  for (; j < e; j += 2) {  // masked tail, 1 pair
    int idx = j + hf;
    int2 p = (idx < e) ? csr[s0 + idx] : make_int2(node, 0);
    float w = __int_as_float(p.y);
    float2 raw = *(const float2*)(t + (size_t)p.x * NH + c4);
    float2 f01 = __half22float2(*(__half2*)&raw.x);
    float2 f23 = __half22float2(*(__half2*)&raw.y);
    a.x += f01.x * w; a.y += f01.y * w; a.z += f23.x * w; a.w += f23.y * w;
  }
  // combine the two edge-halves: lanes 0-31 <- + lanes 32-63
  a.x += __shfl_down(a.x, 32, 64);
  a.y += __shfl_down(a.y, 32, 64);
  a.z += __shfl_down(a.z, 32, 64);
  a.w += __shfl_down(a.w, 32, 64);
  // epilogue: lanes 0-31 hold 4 channels each (lanes 32-63 shadow harmlessly)
  float4 bv = *(const float4*)(bias + c4);
  float4 hv = *(const float4*)(h + (size_t)node * NH + c4);
  float v0 = hv.x + fmaxf(a.x + bv.x, 0.f);
  float v1 = hv.y + fmaxf(a.y + bv.y, 0.f);
  float v2 = hv.z + fmaxf(a.z + bv.z, 0.f);
  float v3 = hv.w + fmaxf(a.w + bv.w, 0.f);
  float s = v0 + v1 + v2 + v3;
  float s2 = v0 * v0 + v1 * v1 + v2 * v2 + v3 * v3;
#pragma unroll
  for (int off = 16; off; off >>= 1) {  // butterfly within 32-lane group
    s += __shfl_xor(s, off, 64);
    s2 += __shfl_xor(s2, off, 64);
  }
  float mean = s * (1.f / 128.f);
  float var = fmaxf(s2 * (1.f / 128.f) - mean * mean, 0.f);
  float inv = rsqrtf(var + 1e-5f);
  float4 gv = *(const float4*)(gamma + c4);
  float4 bt = *(const float4*)(beta + c4);
  float4 o;
  o.x = (v0 - mean) * inv * gv.x + bt.x;
  o.y = (v1 - mean) * inv * gv.y + bt.y;
  o.z = (v2 - mean) * inv * gv.z + bt.z;
  o.w = (v3 - mean) * inv * gv.w + bt.w;
  if (lane < 32) *(float4*)(h + (size_t)node * NH + c4) = o;
  if (Wout) {  // fused readout dot (last layer)
    float4 wv = *(const float4*)(Wout + c4);
    float d = o.x * wv.x + o.y * wv.y + o.z * wv.z + o.w * wv.w;
#pragma unroll
    for (int off = 16; off; off >>= 1) d += __shfl_xor(d, off, 64);
    if (lane == 0) nodeval[node] = d;
  }
}

// ---------------- stage 2: LDS-binned segment reduction ----------------
__global__ __launch_bounds__(256) void reduce_pool_kernel(
    const float* __restrict__ nodeval, const int* __restrict__ batch,
    float* __restrict__ gsum, int* __restrict__ gcnt) {
  __shared__ float bins[NG];
  __shared__ int cbins[NG];
  int tid = threadIdx.x;
  if (tid < NG) {
    bins[tid] = 0.f;
    cbins[tid] = 0;
  }
  __syncthreads();
  int i = blockIdx.x * 256 + tid;
  if (i < NN) {
    int g = batch[i];
    atomicAdd(&bins[g], nodeval[i]);
    atomicAdd(&cbins[g], 1);
  }
  __syncthreads();
  if (tid < NG) {
    if (cbins[tid]) {
      atomicAdd(&gsum[tid], bins[tid]);
      atomicAdd(&gcnt[tid], cbins[tid]);
    }
  }
}

__global__ void finalize_kernel(const float* __restrict__ gsum,
                                const int* __restrict__ gcnt,
                                float* __restrict__ out) {
  int g = threadIdx.x;
  if (g < NG) out[g] = gsum[g] / fmaxf((float)gcnt[g], 1.0f);
}

extern "C" void kernel_launch(void* const* d_in, const int* in_sizes, int n_in,
                              void* d_out, int out_size, void* d_ws, size_t ws_size,
                              hipStream_t stream) {
  const float* x = (const float*)d_in[0];
  const int* eidx = (const int*)d_in[1];
  const int* batch = (const int*)d_in[2];
  const float* W_emb = (const float*)d_in[3];
  const float* b_emb = (const float*)d_in[4];
  const float* W_layers = (const float*)d_in[5];
  const float* b_layers = (const float*)d_in[6];
  const float* ln_gamma = (const float*)d_in[7];
  const float* ln_beta = (const float*)d_in[8];
  const float* W_out = (const float*)d_in[9];
  float* out = (float*)d_out;

  char* ws = (char*)d_ws;
  __half* t = (__half*)ws;      ws += (size_t)NN * NH * 2;
  float* h = (float*)ws;        ws += (size_t)NN * NH * 4;
  short* Whi = (short*)ws;      ws += (size_t)5 * WSLOT * 2;
  short* Wlo = (short*)ws;      ws += (size_t)5 * WSLOT * 2;
  float* dis = (float*)ws;      ws += (size_t)NN * 4;
  int2* csr = (int2*)ws;        ws += (size_t)NE * 8;
  int* rank = (int*)ws;         ws += (size_t)NE * 4;
  int* offs = (int*)ws;         ws += (size_t)NN * 4;
  float* nodeval = (float*)ws;  ws += (size_t)NN * 4;
  int* bsum = (int*)ws;         ws += (size_t)NB * 4;
  int* ebsum = (int*)ws;        ws += (size_t)NB * 4;
  char* zero_base = ws;
  int* cnt = (int*)ws;          ws += (size_t)NN * 4;
  float* gsum = (float*)ws;     ws += (size_t)NG * 4;
  int* gcnt = (int*)ws;         ws += (size_t)NG * 4;
  size_t zero_bytes = (size_t)(ws - zero_base);
  hipMemsetAsync(zero_base, 0, zero_bytes, stream);

  const int* erow = eidx;        // edge_index[0] = sources
  const int* ecol = eidx + NE;   // edge_index[1] = targets

  prep_swizzle<<<(5 * WSLOT + 255) / 256, 256, 0, stream>>>(W_emb, W_layers, Whi,
                                                            Wlo);
  hist_kernel<<<(NE + 255) / 256, 256, 0, stream>>>(ecol, cnt, rank);
  scan1_kernel<<<NB, 256, 0, stream>>>(cnt, bsum, dis);
  scan2_kernel<<<1, 256, 0, stream>>>(bsum, ebsum);
  scan3_kernel<<<NB, 256, 0, stream>>>(cnt, ebsum, offs);
  fill_kernel<<<(NE + 255) / 256, 256, 0, stream>>>(erow, ecol, rank, dis, offs,
                                                    csr);
  int gblk = (NN + 63) / 64;
  gemm_mfma<false><<<gblk, 256, 0, stream>>>(x, Whi, Wlo, b_emb, h, nullptr);
  for (int l = 0; l < NL; ++l) {
    gemm_mfma<true><<<gblk, 256, 0, stream>>>(
        h, Whi + (size_t)(l + 1) * WSLOT, Wlo + (size_t)(l + 1) * WSLOT,
        nullptr, nullptr, t);
    bool last = (l == NL - 1);
    aggregate_kernel<<<(NN + 3) / 4, 256, 0, stream>>>(
        t, h, dis, offs, cnt, csr, b_layers + (size_t)l * NH,
        ln_gamma + (size_t)l * NH, ln_beta + (size_t)l * NH,
        last ? W_out : nullptr, nodeval);
  }
  reduce_pool_kernel<<<(NN + 255) / 256, 256, 0, stream>>>(nodeval, batch, gsum,
                                                           gcnt);
  finalize_kernel<<<1, 64, 0, stream>>>(gsum, gcnt, out);
}

// Round 7
// 397.685 us; speedup vs baseline: 3.7953x; 1.0338x over previous
//
#include <hip/hip_runtime.h>
#include <hip/hip_fp16.h>

#define NN 50000   // nodes
#define NE 800000  // edges
#define NH 128     // hidden
#define NG 32      // graphs
#define NL 4       // layers
#define NB 196     // scan blocks = ceil(NN/256)
#define WSLOT (NH * NH)  // 16384 elements per weight slot

typedef __attribute__((ext_vector_type(8))) short bf16x8;
typedef __attribute__((ext_vector_type(4))) float f32x4;
typedef __attribute__((ext_vector_type(2))) float f32x2;

__device__ inline short f2bf(float x) {
  union { float f; unsigned u; } v;
  v.f = x;
  unsigned r = v.u + 0x7FFF + ((v.u >> 16) & 1);
  return (short)(r >> 16);
}
__device__ inline float bf2f(short s) {
  union { unsigned u; float f; } v;
  v.u = ((unsigned)(unsigned short)s) << 16;
  return v.f;
}

// 256-thread block exclusive scan (wave shuffle + 4-wave combine)
__device__ inline int block_exscan(int v) {
  __shared__ int wsum[4];
  int tid = threadIdx.x, wave = tid >> 6, lane = tid & 63;
  int x = v;
#pragma unroll
  for (int off = 1; off < 64; off <<= 1) {
    int y = __shfl_up(x, off, 64);
    if (lane >= off) x += y;
  }
  if (lane == 63) wsum[wave] = x;
  __syncthreads();
  int wp = 0;
  if (wave > 0) wp += wsum[0];
  if (wave > 1) wp += wsum[1];
  if (wave > 2) wp += wsum[2];
  return wp + x - v;
}

// ---------------- split W into bf16 hi/lo, swizzled into MFMA fragment order ----
// frag layout: idx = ((ks*8 + t)*64 + lane)*8 + j  <->  W[n][k],
//   n = t*16 + (lane&15), k = ks*32 + (lane>>4)*8 + j
// (A- and B-operand fragment layouts are identical for 16x16x32, so this array
//  serves W both as B-operand (f32-out gemm) and as A-operand (fp8-out gemm).)
__global__ __launch_bounds__(256) void prep_swizzle(const float* __restrict__ W_emb,
                                                    const float* __restrict__ W_layers,
                                                    short* __restrict__ hi,
                                                    short* __restrict__ lo) {
  int i = blockIdx.x * 256 + threadIdx.x;
  if (i >= 5 * WSLOT) return;
  int slot = i >> 14, f = i & (WSLOT - 1);
  int j = f & 7, lane = (f >> 3) & 63, tt = (f >> 9) & 7, ks = f >> 12;
  int n = tt * 16 + (lane & 15);
  int k = ks * 32 + ((lane >> 4) & 3) * 8 + j;
  const float* W = slot ? (W_layers + (size_t)(slot - 1) * WSLOT) : W_emb;
  float x = W[n * NH + k];
  short hh = f2bf(x);
  hi[i] = hh;
  lo[i] = f2bf(x - bf2f(hh));
}

// ---------------- degree histogram over targets; atomic return = edge rank ------
__global__ __launch_bounds__(256) void hist_kernel(const int* __restrict__ col,
                                                   int* __restrict__ cnt,
                                                   int* __restrict__ rank) {
  int e = blockIdx.x * 256 + threadIdx.x;
  if (e < NE) rank[e] = atomicAdd(&cnt[col[e]], 1);
}

// ---------------- scan stage 1: per-block sum of cnt, plus dis ----------------
__global__ __launch_bounds__(256) void scan1_kernel(const int* __restrict__ cnt,
                                                    int* __restrict__ bsum,
                                                    float* __restrict__ dis) {
  int i = blockIdx.x * 256 + threadIdx.x;
  int v = (i < NN) ? cnt[i] : 0;
  if (i < NN) dis[i] = rsqrtf((float)(v + 1));
  int lane = threadIdx.x & 63;
  int s = v;
#pragma unroll
  for (int off = 32; off; off >>= 1) s += __shfl_down(s, off, 64);
  __shared__ int ws[4];
  if (lane == 0) ws[threadIdx.x >> 6] = s;
  __syncthreads();
  if (threadIdx.x == 0) bsum[blockIdx.x] = ws[0] + ws[1] + ws[2] + ws[3];
}

// ---------------- scan stage 2: exclusive scan of NB block sums ----------------
__global__ __launch_bounds__(256) void scan2_kernel(const int* __restrict__ bsum,
                                                    int* __restrict__ ebsum) {
  int tid = threadIdx.x;
  int v = (tid < NB) ? bsum[tid] : 0;
  int ex = block_exscan(v);
  if (tid < NB) ebsum[tid] = ex;
}

// ---------------- scan stage 3: block-local scan + block offset ----------------
__global__ __launch_bounds__(256) void scan3_kernel(const int* __restrict__ cnt,
                                                    const int* __restrict__ ebsum,
                                                    int* __restrict__ offs) {
  int i = blockIdx.x * 256 + threadIdx.x;
  int v = (i < NN) ? cnt[i] : 0;
  int ex = block_exscan(v);
  if (i < NN) offs[i] = ebsum[blockIdx.x] + ex;
}

// ---------------- CSR fill (no atomics: rank precomputed by hist) ----------------
__global__ __launch_bounds__(256) void fill_kernel(const int* __restrict__ row,
                                                   const int* __restrict__ col,
                                                   const int* __restrict__ rank,
                                                   const float* __restrict__ dis,
                                                   const int* __restrict__ offs,
                                                   int2* __restrict__ csr) {
  int e = blockIdx.x * 256 + threadIdx.x;
  if (e < NE) {
    int d = col[e];
    int s = row[e];
    int pos = offs[d] + rank[e];
    csr[pos] = make_int2(s, __float_as_int(dis[s] * dis[d]));
  }
}

// ---------------- split-bf16 MFMA GEMM: Y[N,128] = X[N,128] @ W[128,128]^T ------
// FP8_OUT=false: D[m <- A-op(X)][n <- B-op(W)], fp32 float4 row stores (+bias).
// FP8_OUT=true : operands swapped (A-op = W, B-op = X) so each lane holds 4
//                consecutive channels of one node -> pack fp8 dword stores.
template <bool FP8_OUT>
__global__ __launch_bounds__(256) void gemm_mfma(const float* __restrict__ X,
                                                 const short* __restrict__ Whi,
                                                 const short* __restrict__ Wlo,
                                                 const float* __restrict__ bias,
                                                 float* __restrict__ Yf,
                                                 unsigned char* __restrict__ Y8) {
  int wave = threadIdx.x >> 6, lane = threadIdx.x & 63;
  int quad = lane >> 4, r16 = lane & 15;
  int m0 = blockIdx.x * 64 + wave * 16;
  if (m0 >= NN) return;  // NN % 16 == 0
  int mA = m0 + r16;

  f32x4 acc[8];
#pragma unroll
  for (int t = 0; t < 8; ++t) acc[t] = (f32x4){0.f, 0.f, 0.f, 0.f};

#pragma unroll
  for (int ks = 0; ks < 4; ++ks) {
    int klane = ks * 32 + quad * 8;
    const float* xr = X + (size_t)mA * NH + klane;
    float4 a0 = *(const float4*)xr;
    float4 a1 = *(const float4*)(xr + 4);
    float af[8] = {a0.x, a0.y, a0.z, a0.w, a1.x, a1.y, a1.z, a1.w};
    bf16x8 xhi, xlo;
#pragma unroll
    for (int j = 0; j < 8; ++j) {
      short h = f2bf(af[j]);
      xhi[j] = h;
      xlo[j] = f2bf(af[j] - bf2f(h));
    }
#pragma unroll
    for (int t = 0; t < 8; ++t) {
      int fidx = ((ks * 8 + t) * 64 + lane) << 3;
      bf16x8 whi = *(const bf16x8*)(Whi + fidx);
      bf16x8 wlo = *(const bf16x8*)(Wlo + fidx);
      if (FP8_OUT) {  // A-op = W, B-op = X
        acc[t] = __builtin_amdgcn_mfma_f32_16x16x32_bf16(whi, xhi, acc[t], 0, 0, 0);
        acc[t] = __builtin_amdgcn_mfma_f32_16x16x32_bf16(whi, xlo, acc[t], 0, 0, 0);
        acc[t] = __builtin_amdgcn_mfma_f32_16x16x32_bf16(wlo, xhi, acc[t], 0, 0, 0);
      } else {        // A-op = X, B-op = W
        acc[t] = __builtin_amdgcn_mfma_f32_16x16x32_bf16(xhi, whi, acc[t], 0, 0, 0);
        acc[t] = __builtin_amdgcn_mfma_f32_16x16x32_bf16(xlo, whi, acc[t], 0, 0, 0);
        acc[t] = __builtin_amdgcn_mfma_f32_16x16x32_bf16(xhi, wlo, acc[t], 0, 0, 0);
      }
    }
  }
  if (FP8_OUT) {
    // lane holds node m0+r16, channels t*16 + quad*4 + r
    unsigned* dst = (unsigned*)(Y8 + (size_t)(m0 + r16) * NH);
#pragma unroll
    for (int t = 0; t < 8; ++t) {
      int v = 0;
      v = __builtin_amdgcn_cvt_pk_fp8_f32(acc[t][0], acc[t][1], v, 0);
      v = __builtin_amdgcn_cvt_pk_fp8_f32(acc[t][2], acc[t][3], v, 1);
      dst[t * 4 + quad] = (unsigned)v;
    }
  } else {
    int mrow = m0 + quad * 4;
#pragma unroll
    for (int t = 0; t < 8; ++t) {
      int col = t * 16 + r16;
      float bb = bias ? bias[col] : 0.f;
#pragma unroll
      for (int r = 0; r < 4; ++r)
        Yf[(size_t)(mrow + r) * NH + col] = acc[t][r] + bb;
    }
  }
}

// ---------------- fused aggregate + bias + relu + residual + layernorm ----------
// one wave per node; t is fp8 e4m3 (128 B/edge gather); 4 channels/lane x 32
// lanes per edge, 2 edges per wave-instruction.
// When Wout != nullptr (last layer) also emits nodeval = h_new . Wout
__global__ __launch_bounds__(256) void aggregate_kernel(
    const unsigned char* __restrict__ t8, float* __restrict__ h,
    const float* __restrict__ dis, const int* __restrict__ offs,
    const int* __restrict__ cnt, const int2* __restrict__ csr,
    const float* __restrict__ bias, const float* __restrict__ gamma,
    const float* __restrict__ beta, const float* __restrict__ Wout,
    float* __restrict__ nodeval) {
  int node = blockIdx.x * 4 + (threadIdx.x >> 6);
  int lane = threadIdx.x & 63;
  if (node >= NN) return;
  int hf = lane >> 5;        // which edge of the pair
  int c32 = lane & 31;       // dword index within row (4 fp8 channels)
  int c4 = c32 << 2;         // channel base
  const unsigned* t32 = (const unsigned*)t8;
  float dii = dis[node];
  float sl = dii * dii;      // self-loop norm
  float4 a = make_float4(0.f, 0.f, 0.f, 0.f);
  if (hf == 0) {  // self loop handled by half 0
    unsigned raw = t32[(size_t)node * 32 + c32];
    f32x2 lo2 = __builtin_amdgcn_cvt_pk_f32_fp8(raw, 0);
    f32x2 hi2 = __builtin_amdgcn_cvt_pk_f32_fp8(raw, 1);
    a.x = lo2.x * sl; a.y = lo2.y * sl; a.z = hi2.x * sl; a.w = hi2.y * sl;
  }
  int s0 = offs[node];
  int e = cnt[node];
  int j = 0;
  for (; j + 16 <= e; j += 16) {  // 8 pairs
    int2 p[8];
    unsigned raw[8];
#pragma unroll
    for (int u = 0; u < 8; ++u) p[u] = csr[s0 + j + 2 * u + hf];
#pragma unroll
    for (int u = 0; u < 8; ++u) raw[u] = t32[(size_t)p[u].x * 32 + c32];
#pragma unroll
    for (int u = 0; u < 8; ++u) {
      float w = __int_as_float(p[u].y);
      f32x2 lo2 = __builtin_amdgcn_cvt_pk_f32_fp8(raw[u], 0);
      f32x2 hi2 = __builtin_amdgcn_cvt_pk_f32_fp8(raw[u], 1);
      a.x += lo2.x * w; a.y += lo2.y * w; a.z += hi2.x * w; a.w += hi2.y * w;
    }
  }
  for (; j + 8 <= e; j += 8) {  // 4 pairs
    int2 p[4];
    unsigned raw[4];
#pragma unroll
    for (int u = 0; u < 4; ++u) p[u] = csr[s0 + j + 2 * u + hf];
#pragma unroll
    for (int u = 0; u < 4; ++u) raw[u] = t32[(size_t)p[u].x * 32 + c32];
#pragma unroll
    for (int u = 0; u < 4; ++u) {
      float w = __int_as_float(p[u].y);
      f32x2 lo2 = __builtin_amdgcn_cvt_pk_f32_fp8(raw[u], 0);
      f32x2 hi2 = __builtin_amdgcn_cvt_pk_f32_fp8(raw[u], 1);
      a.x += lo2.x * w; a.y += lo2.y * w; a.z += hi2.x * w; a.w += hi2.y * w;
    }
  }
  for (; j < e; j += 2) {  // masked tail, 1 pair
    int idx = j + hf;
    int2 p = (idx < e) ? csr[s0 + idx] : make_int2(node, 0);
    float w = __int_as_float(p.y);
    unsigned raw = t32[(size_t)p.x * 32 + c32];
    f32x2 lo2 = __builtin_amdgcn_cvt_pk_f32_fp8(raw, 0);
    f32x2 hi2 = __builtin_amdgcn_cvt_pk_f32_fp8(raw, 1);
    a.x += lo2.x * w; a.y += lo2.y * w; a.z += hi2.x * w; a.w += hi2.y * w;
  }
  // combine the two edge-halves: lanes 0-31 <- + lanes 32-63
  a.x += __shfl_down(a.x, 32, 64);
  a.y += __shfl_down(a.y, 32, 64);
  a.z += __shfl_down(a.z, 32, 64);
  a.w += __shfl_down(a.w, 32, 64);
  // epilogue: lanes 0-31 hold 4 channels each (lanes 32-63 shadow harmlessly)
  float4 bv = *(const float4*)(bias + c4);
  float4 hv = *(const float4*)(h + (size_t)node * NH + c4);
  float v0 = hv.x + fmaxf(a.x + bv.x, 0.f);
  float v1 = hv.y + fmaxf(a.y + bv.y, 0.f);
  float v2 = hv.z + fmaxf(a.z + bv.z, 0.f);
  float v3 = hv.w + fmaxf(a.w + bv.w, 0.f);
  float s = v0 + v1 + v2 + v3;
  float s2 = v0 * v0 + v1 * v1 + v2 * v2 + v3 * v3;
#pragma unroll
  for (int off = 16; off; off >>= 1) {  // butterfly within 32-lane group
    s += __shfl_xor(s, off, 64);
    s2 += __shfl_xor(s2, off, 64);
  }
  float mean = s * (1.f / 128.f);
  float var = fmaxf(s2 * (1.f / 128.f) - mean * mean, 0.f);
  float inv = rsqrtf(var + 1e-5f);
  float4 gv = *(const float4*)(gamma + c4);
  float4 bt = *(const float4*)(beta + c4);
  float4 o;
  o.x = (v0 - mean) * inv * gv.x + bt.x;
  o.y = (v1 - mean) * inv * gv.y + bt.y;
  o.z = (v2 - mean) * inv * gv.z + bt.z;
  o.w = (v3 - mean) * inv * gv.w + bt.w;
  if (lane < 32) *(float4*)(h + (size_t)node * NH + c4) = o;
  if (Wout) {  // fused readout dot (last layer)
    float4 wv = *(const float4*)(Wout + c4);
    float d = o.x * wv.x + o.y * wv.y + o.z * wv.z + o.w * wv.w;
#pragma unroll
    for (int off = 16; off; off >>= 1) d += __shfl_xor(d, off, 64);
    if (lane == 0) nodeval[node] = d;
  }
}

// ---------------- stage 2: LDS-binned segment reduction ----------------
__global__ __launch_bounds__(256) void reduce_pool_kernel(
    const float* __restrict__ nodeval, const int* __restrict__ batch,
    float* __restrict__ gsum, int* __restrict__ gcnt) {
  __shared__ float bins[NG];
  __shared__ int cbins[NG];
  int tid = threadIdx.x;
  if (tid < NG) {
    bins[tid] = 0.f;
    cbins[tid] = 0;
  }
  __syncthreads();
  int i = blockIdx.x * 256 + tid;
  if (i < NN) {
    int g = batch[i];
    atomicAdd(&bins[g], nodeval[i]);
    atomicAdd(&cbins[g], 1);
  }
  __syncthreads();
  if (tid < NG) {
    if (cbins[tid]) {
      atomicAdd(&gsum[tid], bins[tid]);
      atomicAdd(&gcnt[tid], cbins[tid]);
    }
  }
}

__global__ void finalize_kernel(const float* __restrict__ gsum,
                                const int* __restrict__ gcnt,
                                float* __restrict__ out) {
  int g = threadIdx.x;
  if (g < NG) out[g] = gsum[g] / fmaxf((float)gcnt[g], 1.0f);
}

extern "C" void kernel_launch(void* const* d_in, const int* in_sizes, int n_in,
                              void* d_out, int out_size, void* d_ws, size_t ws_size,
                              hipStream_t stream) {
  const float* x = (const float*)d_in[0];
  const int* eidx = (const int*)d_in[1];
  const int* batch = (const int*)d_in[2];
  const float* W_emb = (const float*)d_in[3];
  const float* b_emb = (const float*)d_in[4];
  const float* W_layers = (const float*)d_in[5];
  const float* b_layers = (const float*)d_in[6];
  const float* ln_gamma = (const float*)d_in[7];
  const float* ln_beta = (const float*)d_in[8];
  const float* W_out = (const float*)d_in[9];
  float* out = (float*)d_out;

  char* ws = (char*)d_ws;
  unsigned char* t8 = (unsigned char*)ws; ws += (size_t)NN * NH;  // fp8 messages
  float* h = (float*)ws;        ws += (size_t)NN * NH * 4;
  short* Whi = (short*)ws;      ws += (size_t)5 * WSLOT * 2;
  short* Wlo = (short*)ws;      ws += (size_t)5 * WSLOT * 2;
  float* dis = (float*)ws;      ws += (size_t)NN * 4;
  int2* csr = (int2*)ws;        ws += (size_t)NE * 8;
  int* rank = (int*)ws;         ws += (size_t)NE * 4;
  int* offs = (int*)ws;         ws += (size_t)NN * 4;
  float* nodeval = (float*)ws;  ws += (size_t)NN * 4;
  int* bsum = (int*)ws;         ws += (size_t)NB * 4;
  int* ebsum = (int*)ws;        ws += (size_t)NB * 4;
  char* zero_base = ws;
  int* cnt = (int*)ws;          ws += (size_t)NN * 4;
  float* gsum = (float*)ws;     ws += (size_t)NG * 4;
  int* gcnt = (int*)ws;         ws += (size_t)NG * 4;
  size_t zero_bytes = (size_t)(ws - zero_base);
  hipMemsetAsync(zero_base, 0, zero_bytes, stream);

  const int* erow = eidx;        // edge_index[0] = sources
  const int* ecol = eidx + NE;   // edge_index[1] = targets

  prep_swizzle<<<(5 * WSLOT + 255) / 256, 256, 0, stream>>>(W_emb, W_layers, Whi,
                                                            Wlo);
  hist_kernel<<<(NE + 255) / 256, 256, 0, stream>>>(ecol, cnt, rank);
  scan1_kernel<<<NB, 256, 0, stream>>>(cnt, bsum, dis);
  scan2_kernel<<<1, 256, 0, stream>>>(bsum, ebsum);
  scan3_kernel<<<NB, 256, 0, stream>>>(cnt, ebsum, offs);
  fill_kernel<<<(NE + 255) / 256, 256, 0, stream>>>(erow, ecol, rank, dis, offs,
                                                    csr);
  int gblk = (NN + 63) / 64;
  gemm_mfma<false><<<gblk, 256, 0, stream>>>(x, Whi, Wlo, b_emb, h, nullptr);
  for (int l = 0; l < NL; ++l) {
    gemm_mfma<true><<<gblk, 256, 0, stream>>>(
        h, Whi + (size_t)(l + 1) * WSLOT, Wlo + (size_t)(l + 1) * WSLOT,
        nullptr, nullptr, t8);
    bool last = (l == NL - 1);
    aggregate_kernel<<<(NN + 3) / 4, 256, 0, stream>>>(
        t8, h, dis, offs, cnt, csr, b_layers + (size_t)l * NH,
        ln_gamma + (size_t)l * NH, ln_beta + (size_t)l * NH,
        last ? W_out : nullptr, nodeval);
  }
  reduce_pool_kernel<<<(NN + 255) / 256, 256, 0, stream>>>(nodeval, batch, gsum,
                                                           gcnt);
  finalize_kernel<<<1, 64, 0, stream>>>(gsum, gcnt, out);
}